// Round 2
// 286.747 us; speedup vs baseline: 1.1531x; 1.1531x over previous
//
#include <hip/hip_runtime.h>
#include <math.h>

// DeltaNetTemporal: B=16, N=4096, C=256, H=4, D=64.  All I/O fp32.
// R6: state_pass eliminated by linearity:
//   y    = x @ (0.95*S[b,h] @ Wq_h)^T           (fold + GEMM)
//   pred-sums: kbsum = sum(beta*k'), err = (Wv@xbsum - Sd@kbsum)/4096
//   v-GEMM eliminated: sum(beta*v) = Wv @ sum(beta*x)
// R7: beta_xbsum was latency-bound (1 wave/SIMD, serial load->shfl chain,
//   72us @ 490 GB/s). Now 1024 blocks (4 waves/SIMD), rotated-loop load
//   prefetch, betas staged in LDS and stored coalesced once per block.
// R8: identical resubmit of R7 (previous bench failed at container level,
//   no counters; kernel audit found no OOB/race/deadlock).
// Pipeline: memset -> beta+xbsum -> kGEMM(+elu/L2norm/col-sum epilogue)
//           -> fold M -> 2x[ yGEMM(+rowssq) -> outGEMM(RMSNorm-on-stage) ] -> finalize.
// Workspace 19.3 MB.

typedef _Float16 f16;
typedef f16 f16x8 __attribute__((ext_vector_type(8)));
typedef float f32x4 __attribute__((ext_vector_type(4)));

__device__ __forceinline__ f16x8 cvt8(const float* q) {
  float4 a = *(const float4*)q;
  float4 b = *(const float4*)(q + 4);
  f16x8 r;
  r[0] = (f16)a.x; r[1] = (f16)a.y; r[2] = (f16)a.z; r[3] = (f16)a.w;
  r[4] = (f16)b.x; r[5] = (f16)b.y; r[6] = (f16)b.z; r[7] = (f16)b.w;
  return r;
}

// ---------------- beta + xbsum ----------------
// grid 1024: b = blk>>6, tile = blk&63 (64 rows/block, 16 rows/wave).
// beta = sigmoid(x.Wb[h]); xbsum[b,h,:] += beta * x
// (register accum -> LDS -> global atomics). Betas staged in LDS,
// one coalesced store per block.
__global__ __launch_bounds__(256) void beta_xbsum(
    const float* __restrict__ x, const float* __restrict__ Wb,
    float* __restrict__ betaArr, float* __restrict__ xbsum) {
  const int t = threadIdx.x;
  const int wave = t >> 6, lane = t & 63;
  const int b = blockIdx.x >> 6;
  const int tile = blockIdx.x & 63;
  float4 wb[4];
#pragma unroll
  for (int h = 0; h < 4; ++h) wb[h] = *(const float4*)(Wb + h * 256 + lane * 4);
  float xacc[4][4] = {};  // [h][j], c = lane*4+j
  const size_t rowbase = (size_t)b * 4096 + tile * 64;
  __shared__ float bsh[4][64];   // [h][row-in-tile]
  // rotated loop: next row's load issued before current row's shfl chains
  float4 xv = *(const float4*)(x + (rowbase + wave) * 256 + lane * 4);
#pragma unroll 2
  for (int i = 0; i < 16; ++i) {
    int r = i * 4 + wave;
    float4 nx = xv;
    if (i < 15)
      nx = *(const float4*)(x + (rowbase + r + 4) * 256 + lane * 4);
#pragma unroll
    for (int h = 0; h < 4; ++h) {
      float s = xv.x * wb[h].x + xv.y * wb[h].y + xv.z * wb[h].z + xv.w * wb[h].w;
#pragma unroll
      for (int off = 32; off; off >>= 1) s += __shfl_xor(s, off);
      float bh = 1.f / (1.f + __expf(-s));
      if (lane == h) bsh[h][r] = bh;  // rows disjoint per wave: no race
      xacc[h][0] += bh * xv.x; xacc[h][1] += bh * xv.y;
      xacc[h][2] += bh * xv.z; xacc[h][3] += bh * xv.w;
    }
    xv = nx;
  }
  __shared__ float xbp[4][4][256];  // [wave][h][c]
#pragma unroll
  for (int h = 0; h < 4; ++h)
#pragma unroll
    for (int j = 0; j < 4; ++j) xbp[wave][h][lane * 4 + j] = xacc[h][j];
  __syncthreads();
  // coalesced beta store: 256 values = 4 heads x 64 rows
  {
    int h = t >> 6, r = t & 63;
    betaArr[((size_t)(b * 4 + h) << 12) + tile * 64 + r] = bsh[h][r];
  }
  for (int idx = t; idx < 1024; idx += 256) {
    int h = idx >> 8, c = idx & 255;
    float s = xbp[0][h][c] + xbp[1][h][c] + xbp[2][h][c] + xbp[3][h][c];
    atomicAdd(&xbsum[(b * 4 + h) * 256 + c], s);
  }
}

// ---------------- k-GEMM with elu/L2norm/col-sum epilogue ----------------
// k = x @ Wk^T, k' = elu(k)+1 normalized per (token,head); accumulates
// ksum[bh][d] += k', kbsum[bh][d] += beta*k'. k never written to HBM.
__global__ __launch_bounds__(256) void kgemm_sums(
    const float* __restrict__ x, const float* __restrict__ Wk,
    const float* __restrict__ betaArr,
    float* __restrict__ ksum, float* __restrict__ kbsum) {
  __shared__ union {
    struct { f16 A[128][72]; f16 B[128][72]; } s;
    f16 K[128][132];
  } u;
  __shared__ float bstage[2][128];
  const int t = threadIdx.x;
  const int m0 = blockIdx.y * 128;
  const int n0 = blockIdx.x * 128;  // heads n0>>6 .. +1
  const int b = m0 >> 12;
  const int wave = t >> 6, lane = t & 63;
  const int wm = (wave >> 1) * 64, wn = (wave & 1) * 64;
  const int fr = lane & 15, fq = lane >> 4;
  {
    int hh = t >> 7, r = t & 127;
    bstage[hh][r] =
        betaArr[((size_t)(b * 4 + (n0 >> 6) + hh) << 12) + (m0 & 4095) + r];
  }
  f32x4 acc[4][4] = {};
#pragma unroll 1
  for (int kt = 0; kt < 4; ++kt) {
    const int k0 = kt * 64;
#pragma unroll
    for (int i = 0; i < 4; ++i) {
      int id = i * 256 + t;
      int row = id >> 3, cc = id & 7;
      *(f16x8*)&u.s.A[row][cc * 8] =
          cvt8(x + (size_t)(m0 + row) * 256 + k0 + cc * 8);
      *(f16x8*)&u.s.B[row][cc * 8] =
          cvt8(Wk + (size_t)(n0 + row) * 256 + k0 + cc * 8);
    }
    __syncthreads();
#pragma unroll
    for (int ks = 0; ks < 2; ++ks) {
      f16x8 afr[4], bfr[4];
#pragma unroll
      for (int mi = 0; mi < 4; ++mi)
        afr[mi] = *(const f16x8*)&u.s.A[wm + mi * 16 + fr][ks * 32 + fq * 8];
#pragma unroll
      for (int ni = 0; ni < 4; ++ni)
        bfr[ni] = *(const f16x8*)&u.s.B[wn + ni * 16 + fr][ks * 32 + fq * 8];
#pragma unroll
      for (int mi = 0; mi < 4; ++mi)
#pragma unroll
        for (int ni = 0; ni < 4; ++ni)
          acc[mi][ni] = __builtin_amdgcn_mfma_f32_16x16x32_f16(
              afr[mi], bfr[ni], acc[mi][ni], 0, 0, 0);
    }
    __syncthreads();
  }
  // elu+1, L2-normalize per (row, head) — head == this wave's 64-col range.
#pragma unroll
  for (int mi = 0; mi < 4; ++mi)
#pragma unroll
    for (int rr = 0; rr < 4; ++rr) {
      float s = 0.f;
#pragma unroll
      for (int ni = 0; ni < 4; ++ni) {
        float v = acc[mi][ni][rr];
        v = v > 0.f ? v + 1.f : __expf(v);
        acc[mi][ni][rr] = v;
        s += v * v;
      }
#pragma unroll
      for (int off = 1; off < 16; off <<= 1) s += __shfl_xor(s, off);
      float inv = 1.f / (sqrtf(s) + 1e-6f);
#pragma unroll
      for (int ni = 0; ni < 4; ++ni) acc[mi][ni][rr] *= inv;
    }
  // k' -> LDS (aliases A/B staging; all waves past final barrier)
#pragma unroll
  for (int mi = 0; mi < 4; ++mi)
#pragma unroll
    for (int ni = 0; ni < 4; ++ni)
#pragma unroll
      for (int rr = 0; rr < 4; ++rr)
        u.K[wm + mi * 16 + fq * 4 + rr][wn + ni * 16 + fr] = (f16)acc[mi][ni][rr];
  __syncthreads();
  if (t < 128) {
    const int c = t, hl = c >> 6;
    float sk = 0.f, skb = 0.f;
#pragma unroll 4
    for (int r = 0; r < 128; ++r) {
      float v = (float)u.K[r][c];
      float be = bstage[hl][r];
      sk += v;
      skb += be * v;
    }
    int gh = b * 4 + (n0 >> 6) + hl;
    atomicAdd(&ksum[gh * 64 + (c & 63)], sk);
    atomicAdd(&kbsum[gh * 64 + (c & 63)], skb);
  }
}

// ---------------- fold: M[b][(h,d)][c] = 0.95 * S[b,h] @ Wq_h ----------------
__global__ __launch_bounds__(256) void fold_M(
    const float* __restrict__ S, const float* __restrict__ Wq,
    f16* __restrict__ M) {
  const int bh = blockIdx.x;
  const int h = bh & 3;
  const int t = threadIdx.x;  // column c
  __shared__ float Sl[64][64];
  for (int i = t; i < 4096; i += 256)
    ((float*)Sl)[i] = 0.95f * S[(size_t)bh * 4096 + i];
  __syncthreads();
  float m[64] = {};
#pragma unroll 1
  for (int e = 0; e < 64; ++e) {
    float wv = Wq[(size_t)(h * 64 + e) * 256 + t];
#pragma unroll
    for (int d = 0; d < 64; ++d) m[d] += Sl[d][e] * wv;
  }
  f16* Mb = M + (size_t)(bh >> 2) * 65536;
#pragma unroll
  for (int d = 0; d < 64; ++d)
    Mb[(size_t)(h * 64 + d) * 256 + t] = (f16)m[d];
}

// ---------------- y-GEMM: y = x @ M[b]^T, + per-row sumsq atomics ----------------
__global__ __launch_bounds__(256) void ygemm_ssq(
    const float* __restrict__ x, int m_base, const f16* __restrict__ M,
    f16* __restrict__ y, float* __restrict__ rowssq) {
  __shared__ f16 As[128][72];
  __shared__ f16 Bs[128][72];
  const int t = threadIdx.x;
  const int m0 = blockIdx.y * 128;  // local row within half
  const int n0 = blockIdx.x * 128;
  const int b = (m_base + m0) >> 12;
  const f16* Mb = M + (size_t)b * 65536;
  const int wave = t >> 6, lane = t & 63;
  const int wm = (wave >> 1) * 64, wn = (wave & 1) * 64;
  const int fr = lane & 15, fq = lane >> 4;
  f32x4 acc[4][4] = {};
#pragma unroll 1
  for (int kt = 0; kt < 4; ++kt) {
    const int k0 = kt * 64;
#pragma unroll
    for (int i = 0; i < 4; ++i) {
      int id = i * 256 + t;
      int row = id >> 3, cc = id & 7;
      *(f16x8*)&As[row][cc * 8] =
          cvt8(x + (size_t)(m_base + m0 + row) * 256 + k0 + cc * 8);
      *(uint4*)&Bs[row][cc * 8] =
          *(const uint4*)(Mb + (size_t)(n0 + row) * 256 + k0 + cc * 8);
    }
    __syncthreads();
#pragma unroll
    for (int ks = 0; ks < 2; ++ks) {
      f16x8 afr[4], bfr[4];
#pragma unroll
      for (int mi = 0; mi < 4; ++mi)
        afr[mi] = *(const f16x8*)&As[wm + mi * 16 + fr][ks * 32 + fq * 8];
#pragma unroll
      for (int ni = 0; ni < 4; ++ni)
        bfr[ni] = *(const f16x8*)&Bs[wn + ni * 16 + fr][ks * 32 + fq * 8];
#pragma unroll
      for (int mi = 0; mi < 4; ++mi)
#pragma unroll
        for (int ni = 0; ni < 4; ++ni)
          acc[mi][ni] = __builtin_amdgcn_mfma_f32_16x16x32_f16(
              afr[mi], bfr[ni], acc[mi][ni], 0, 0, 0);
    }
    __syncthreads();
  }
#pragma unroll
  for (int mi = 0; mi < 4; ++mi)
#pragma unroll
    for (int rr = 0; rr < 4; ++rr) {
      float s = 0.f;
#pragma unroll
      for (int ni = 0; ni < 4; ++ni) {
        float v = acc[mi][ni][rr];
        s += v * v;
        int row = m0 + wm + mi * 16 + fq * 4 + rr;
        int col = n0 + wn + ni * 16 + fr;
        y[(size_t)row * 256 + col] = (f16)v;
      }
#pragma unroll
      for (int off = 1; off < 16; off <<= 1) s += __shfl_xor(s, off);
      if (fr == 0)
        atomicAdd(&rowssq[m0 + wm + mi * 16 + fq * 4 + rr], s);
    }
}

// ---------------- out-GEMM: out = RMSNorm(y)*g @ Wo^T ----------------
__global__ __launch_bounds__(256) void ogemm_scaled(
    const f16* __restrict__ y, const float* __restrict__ rowssq,
    const float* __restrict__ g_rms, const float* __restrict__ Wo,
    float* __restrict__ out, int m_base) {
  __shared__ f16 As[128][72];
  __shared__ f16 Bs[128][72];
  const int t = threadIdx.x;
  const int m0 = blockIdx.y * 128;  // local row within half
  const int n0 = blockIdx.x * 128;
  const int wave = t >> 6, lane = t & 63;
  const int wm = (wave >> 1) * 64, wn = (wave & 1) * 64;
  const int fr = lane & 15, fq = lane >> 4;
  f32x4 acc[4][4] = {};
#pragma unroll 1
  for (int kt = 0; kt < 4; ++kt) {
    const int k0 = kt * 64;
#pragma unroll
    for (int i = 0; i < 4; ++i) {
      int id = i * 256 + t;
      int row = id >> 3, cc = id & 7;
      float rs = rsqrtf(rowssq[m0 + row] * (1.f / 256.f) + 1e-6f);
      const f16* yp = y + (size_t)(m0 + row) * 256 + k0 + cc * 8;
      const float* gp = g_rms + k0 + cc * 8;
      f16x8 a;
#pragma unroll
      for (int j = 0; j < 8; ++j) a[j] = (f16)((float)yp[j] * rs * gp[j]);
      *(f16x8*)&As[row][cc * 8] = a;
      *(f16x8*)&Bs[row][cc * 8] =
          cvt8(Wo + (size_t)(n0 + row) * 256 + k0 + cc * 8);
    }
    __syncthreads();
#pragma unroll
    for (int ks = 0; ks < 2; ++ks) {
      f16x8 afr[4], bfr[4];
#pragma unroll
      for (int mi = 0; mi < 4; ++mi)
        afr[mi] = *(const f16x8*)&As[wm + mi * 16 + fr][ks * 32 + fq * 8];
#pragma unroll
      for (int ni = 0; ni < 4; ++ni)
        bfr[ni] = *(const f16x8*)&Bs[wn + ni * 16 + fr][ks * 32 + fq * 8];
#pragma unroll
      for (int mi = 0; mi < 4; ++mi)
#pragma unroll
        for (int ni = 0; ni < 4; ++ni)
          acc[mi][ni] = __builtin_amdgcn_mfma_f32_16x16x32_f16(
              afr[mi], bfr[ni], acc[mi][ni], 0, 0, 0);
    }
    __syncthreads();
  }
#pragma unroll
  for (int mi = 0; mi < 4; ++mi)
#pragma unroll
    for (int ni = 0; ni < 4; ++ni)
#pragma unroll
      for (int rr = 0; rr < 4; ++rr) {
        int row = m_base + m0 + wm + mi * 16 + fq * 4 + rr;
        int col = n0 + wn + ni * 16 + fr;
        out[(size_t)row * 256 + col] = acc[mi][ni][rr];
      }
}

// ---------------- finalize S ----------------
// err = (Wv_h @ xbsum - 0.95*S @ kbsum)/4096 ; key = ksum/4096
// S_new = clip(0.95*S + outer(err, key), +-10)
__global__ __launch_bounds__(256) void finalize_S(
    const float* __restrict__ S, const float* __restrict__ Wv,
    const float* __restrict__ xbsum, const float* __restrict__ ksum,
    const float* __restrict__ kbsum, float* __restrict__ Sout) {
  const int bh = blockIdx.x;
  const int h = bh & 3;
  const int t = threadIdx.x;
  const int wave = t >> 6, lane = t & 63;
  __shared__ float xb[256], kb[64], key[64], errv[64];
  xb[t] = xbsum[bh * 256 + t];
  if (t < 64) {
    kb[t] = kbsum[bh * 64 + t];
    key[t] = ksum[bh * 64 + t] * (1.f / 4096.f);
  }
  __syncthreads();
#pragma unroll 1
  for (int ri = 0; ri < 16; ++ri) {
    int i = wave * 16 + ri;
    float4 wv4 = *(const float4*)(Wv + (size_t)(h * 64 + i) * 256 + lane * 4);
    float4 xb4 = *(const float4*)(&xb[lane * 4]);
    float s = wv4.x * xb4.x + wv4.y * xb4.y + wv4.z * xb4.z + wv4.w * xb4.w;
    s -= 0.95f * S[(size_t)bh * 4096 + i * 64 + lane] * kb[lane];
#pragma unroll
    for (int off = 32; off; off >>= 1) s += __shfl_xor(s, off);
    if (lane == 0) errv[i] = s * (1.f / 4096.f);
  }
  __syncthreads();
  for (int idx = t; idx < 4096; idx += 256) {
    int i = idx >> 6, j = idx & 63;
    float v = 0.95f * S[(size_t)bh * 4096 + idx] + errv[i] * key[j];
    Sout[(size_t)bh * 4096 + idx] = fminf(10.f, fmaxf(-10.f, v));
  }
}

extern "C" void kernel_launch(void* const* d_in, const int* in_sizes, int n_in,
                              void* d_out, int out_size, void* d_ws, size_t ws_size,
                              hipStream_t stream) {
  const float* x  = (const float*)d_in[0];
  const float* S  = (const float*)d_in[1];
  const float* Wq = (const float*)d_in[2];
  const float* Wk = (const float*)d_in[3];
  const float* Wv = (const float*)d_in[4];
  const float* Wb = (const float*)d_in[5];
  const float* Wo = (const float*)d_in[6];
  const float* g  = (const float*)d_in[7];

  char* w = (char*)d_ws;
  float* betaArr = (float*)w;                    // 1,048,576 B
  f16*   M       = (f16*)(w + 1048576);          // 2,097,152 B
  f16*   y       = (f16*)(w + 3145728);          // 16,777,216 B (32768x256)
  float* rowssq  = (float*)(w + 19922944);       // 262,144 B (2 halves)
  float* xbsum   = (float*)(w + 20185088);       // 65,536 B
  float* ksum    = (float*)(w + 20250624);       // 16,384 B
  float* kbsum   = (float*)(w + 20267008);       // 16,384 B

  float* out  = (float*)d_out;                   // [16,4096,256] fp32
  float* Sout = out + (size_t)16 * 4096 * 256;   // [16,4,64,64]  fp32

  hipMemsetAsync(w + 19922944, 0, 360448, stream);  // rowssq..kbsum
  beta_xbsum<<<1024, 256, 0, stream>>>(x, Wb, betaArr, xbsum);
  kgemm_sums<<<dim3(2, 512), 256, 0, stream>>>(x, Wk, betaArr, ksum, kbsum);
  fold_M<<<64, 256, 0, stream>>>(S, Wq, M);
  for (int half = 0; half < 2; ++half) {
    int m_base = half * 32768;
    ygemm_ssq<<<dim3(2, 256), 256, 0, stream>>>(x, m_base, M, y,
                                                rowssq + half * 32768);
    ogemm_scaled<<<dim3(2, 256), 256, 0, stream>>>(y, rowssq + half * 32768, g,
                                                   Wo, out, m_base);
  }
  finalize_S<<<64, 256, 0, stream>>>(S, Wv, xbsum, ksum, kbsum, Sout);
}

// Round 3
// 250.680 us; speedup vs baseline: 1.3190x; 1.1439x over previous
//
#include <hip/hip_runtime.h>
#include <math.h>

// DeltaNetTemporal: B=16, N=4096, C=256, H=4, D=64.  All I/O fp32.
// R6: state_pass eliminated by linearity:
//   y    = x @ (0.95*S[b,h] @ Wq_h)^T           (fold + GEMM)
//   pred-sums: kbsum = sum(beta*k'), err = (Wv@xbsum - Sd@kbsum)/4096
//   v-GEMM eliminated: sum(beta*v) = Wv @ sum(beta*x)
// R7/R8: beta_xbsum latency fix (1024 blocks, prefetch, coalesced beta store):
//   330.6 -> 286.7 us.
// R9: fold_M was latency-bound (64 blocks = 64/256 CUs, 1 wave/SIMD, 4096
//   broadcast ds_reads/thread; 46 us @ 2.5% occupancy, VALUBusy 1.8%).
//   Now 512 blocks (64 bh x 8 d-slices), no LDS: S reads are wave-uniform
//   -> scalar loads; per-thread m[8] over coalesced Wq columns, e-loop
//   unrolled x4 to keep loads in flight. 0.95 applied at store.
// Pipeline: memset -> beta+xbsum -> kGEMM(+elu/L2norm/col-sum epilogue)
//           -> fold M -> 2x[ yGEMM(+rowssq) -> outGEMM(RMSNorm-on-stage) ] -> finalize.
// Workspace 19.3 MB.

typedef _Float16 f16;
typedef f16 f16x8 __attribute__((ext_vector_type(8)));
typedef float f32x4 __attribute__((ext_vector_type(4)));

__device__ __forceinline__ f16x8 cvt8(const float* q) {
  float4 a = *(const float4*)q;
  float4 b = *(const float4*)(q + 4);
  f16x8 r;
  r[0] = (f16)a.x; r[1] = (f16)a.y; r[2] = (f16)a.z; r[3] = (f16)a.w;
  r[4] = (f16)b.x; r[5] = (f16)b.y; r[6] = (f16)b.z; r[7] = (f16)b.w;
  return r;
}

// ---------------- beta + xbsum ----------------
// grid 1024: b = blk>>6, tile = blk&63 (64 rows/block, 16 rows/wave).
// beta = sigmoid(x.Wb[h]); xbsum[b,h,:] += beta * x
// (register accum -> LDS -> global atomics). Betas staged in LDS,
// one coalesced store per block.
__global__ __launch_bounds__(256) void beta_xbsum(
    const float* __restrict__ x, const float* __restrict__ Wb,
    float* __restrict__ betaArr, float* __restrict__ xbsum) {
  const int t = threadIdx.x;
  const int wave = t >> 6, lane = t & 63;
  const int b = blockIdx.x >> 6;
  const int tile = blockIdx.x & 63;
  float4 wb[4];
#pragma unroll
  for (int h = 0; h < 4; ++h) wb[h] = *(const float4*)(Wb + h * 256 + lane * 4);
  float xacc[4][4] = {};  // [h][j], c = lane*4+j
  const size_t rowbase = (size_t)b * 4096 + tile * 64;
  __shared__ float bsh[4][64];   // [h][row-in-tile]
  // rotated loop: next row's load issued before current row's shfl chains
  float4 xv = *(const float4*)(x + (rowbase + wave) * 256 + lane * 4);
#pragma unroll 2
  for (int i = 0; i < 16; ++i) {
    int r = i * 4 + wave;
    float4 nx = xv;
    if (i < 15)
      nx = *(const float4*)(x + (rowbase + r + 4) * 256 + lane * 4);
#pragma unroll
    for (int h = 0; h < 4; ++h) {
      float s = xv.x * wb[h].x + xv.y * wb[h].y + xv.z * wb[h].z + xv.w * wb[h].w;
#pragma unroll
      for (int off = 32; off; off >>= 1) s += __shfl_xor(s, off);
      float bh = 1.f / (1.f + __expf(-s));
      if (lane == h) bsh[h][r] = bh;  // rows disjoint per wave: no race
      xacc[h][0] += bh * xv.x; xacc[h][1] += bh * xv.y;
      xacc[h][2] += bh * xv.z; xacc[h][3] += bh * xv.w;
    }
    xv = nx;
  }
  __shared__ float xbp[4][4][256];  // [wave][h][c]
#pragma unroll
  for (int h = 0; h < 4; ++h)
#pragma unroll
    for (int j = 0; j < 4; ++j) xbp[wave][h][lane * 4 + j] = xacc[h][j];
  __syncthreads();
  // coalesced beta store: 256 values = 4 heads x 64 rows
  {
    int h = t >> 6, r = t & 63;
    betaArr[((size_t)(b * 4 + h) << 12) + tile * 64 + r] = bsh[h][r];
  }
  for (int idx = t; idx < 1024; idx += 256) {
    int h = idx >> 8, c = idx & 255;
    float s = xbp[0][h][c] + xbp[1][h][c] + xbp[2][h][c] + xbp[3][h][c];
    atomicAdd(&xbsum[(b * 4 + h) * 256 + c], s);
  }
}

// ---------------- k-GEMM with elu/L2norm/col-sum epilogue ----------------
// k = x @ Wk^T, k' = elu(k)+1 normalized per (token,head); accumulates
// ksum[bh][d] += k', kbsum[bh][d] += beta*k'. k never written to HBM.
__global__ __launch_bounds__(256) void kgemm_sums(
    const float* __restrict__ x, const float* __restrict__ Wk,
    const float* __restrict__ betaArr,
    float* __restrict__ ksum, float* __restrict__ kbsum) {
  __shared__ union {
    struct { f16 A[128][72]; f16 B[128][72]; } s;
    f16 K[128][132];
  } u;
  __shared__ float bstage[2][128];
  const int t = threadIdx.x;
  const int m0 = blockIdx.y * 128;
  const int n0 = blockIdx.x * 128;  // heads n0>>6 .. +1
  const int b = m0 >> 12;
  const int wave = t >> 6, lane = t & 63;
  const int wm = (wave >> 1) * 64, wn = (wave & 1) * 64;
  const int fr = lane & 15, fq = lane >> 4;
  {
    int hh = t >> 7, r = t & 127;
    bstage[hh][r] =
        betaArr[((size_t)(b * 4 + (n0 >> 6) + hh) << 12) + (m0 & 4095) + r];
  }
  f32x4 acc[4][4] = {};
#pragma unroll 1
  for (int kt = 0; kt < 4; ++kt) {
    const int k0 = kt * 64;
#pragma unroll
    for (int i = 0; i < 4; ++i) {
      int id = i * 256 + t;
      int row = id >> 3, cc = id & 7;
      *(f16x8*)&u.s.A[row][cc * 8] =
          cvt8(x + (size_t)(m0 + row) * 256 + k0 + cc * 8);
      *(f16x8*)&u.s.B[row][cc * 8] =
          cvt8(Wk + (size_t)(n0 + row) * 256 + k0 + cc * 8);
    }
    __syncthreads();
#pragma unroll
    for (int ks = 0; ks < 2; ++ks) {
      f16x8 afr[4], bfr[4];
#pragma unroll
      for (int mi = 0; mi < 4; ++mi)
        afr[mi] = *(const f16x8*)&u.s.A[wm + mi * 16 + fr][ks * 32 + fq * 8];
#pragma unroll
      for (int ni = 0; ni < 4; ++ni)
        bfr[ni] = *(const f16x8*)&u.s.B[wn + ni * 16 + fr][ks * 32 + fq * 8];
#pragma unroll
      for (int mi = 0; mi < 4; ++mi)
#pragma unroll
        for (int ni = 0; ni < 4; ++ni)
          acc[mi][ni] = __builtin_amdgcn_mfma_f32_16x16x32_f16(
              afr[mi], bfr[ni], acc[mi][ni], 0, 0, 0);
    }
    __syncthreads();
  }
  // elu+1, L2-normalize per (row, head) — head == this wave's 64-col range.
#pragma unroll
  for (int mi = 0; mi < 4; ++mi)
#pragma unroll
    for (int rr = 0; rr < 4; ++rr) {
      float s = 0.f;
#pragma unroll
      for (int ni = 0; ni < 4; ++ni) {
        float v = acc[mi][ni][rr];
        v = v > 0.f ? v + 1.f : __expf(v);
        acc[mi][ni][rr] = v;
        s += v * v;
      }
#pragma unroll
      for (int off = 1; off < 16; off <<= 1) s += __shfl_xor(s, off);
      float inv = 1.f / (sqrtf(s) + 1e-6f);
#pragma unroll
      for (int ni = 0; ni < 4; ++ni) acc[mi][ni][rr] *= inv;
    }
  // k' -> LDS (aliases A/B staging; all waves past final barrier)
#pragma unroll
  for (int mi = 0; mi < 4; ++mi)
#pragma unroll
    for (int ni = 0; ni < 4; ++ni)
#pragma unroll
      for (int rr = 0; rr < 4; ++rr)
        u.K[wm + mi * 16 + fq * 4 + rr][wn + ni * 16 + fr] = (f16)acc[mi][ni][rr];
  __syncthreads();
  if (t < 128) {
    const int c = t, hl = c >> 6;
    float sk = 0.f, skb = 0.f;
#pragma unroll 4
    for (int r = 0; r < 128; ++r) {
      float v = (float)u.K[r][c];
      float be = bstage[hl][r];
      sk += v;
      skb += be * v;
    }
    int gh = b * 4 + (n0 >> 6) + hl;
    atomicAdd(&ksum[gh * 64 + (c & 63)], sk);
    atomicAdd(&kbsum[gh * 64 + (c & 63)], skb);
  }
}

// ---------------- fold: M[b][(h,d)][c] = 0.95 * S[b,h] @ Wq_h ----------------
// R9: grid (8,64): blockIdx.y = bh, blockIdx.x = dq (8 d-rows each).
// Thread t = output column. S reads are wave-uniform -> scalar loads, no LDS.
__global__ __launch_bounds__(256) void fold_M(
    const float* __restrict__ S, const float* __restrict__ Wq,
    f16* __restrict__ M) {
  const int bh = blockIdx.y;
  const int dq = blockIdx.x;      // d-rows [dq*8, dq*8+8)
  const int h = bh & 3;
  const int t = threadIdx.x;      // column c
  const float* Sp = S + (size_t)bh * 4096 + dq * 8 * 64;  // [8][64]
  const float* Wp = Wq + (size_t)h * 64 * 256 + t;
  float m[8] = {};
#pragma unroll 4
  for (int e = 0; e < 64; ++e) {
    float wv = Wp[e * 256];
#pragma unroll
    for (int dd = 0; dd < 8; ++dd) m[dd] += Sp[dd * 64 + e] * wv;
  }
  f16* Mb = M + (size_t)(bh >> 2) * 65536;
#pragma unroll
  for (int dd = 0; dd < 8; ++dd)
    Mb[(size_t)(h * 64 + dq * 8 + dd) * 256 + t] = (f16)(0.95f * m[dd]);
}

// ---------------- y-GEMM: y = x @ M[b]^T, + per-row sumsq atomics ----------------
__global__ __launch_bounds__(256) void ygemm_ssq(
    const float* __restrict__ x, int m_base, const f16* __restrict__ M,
    f16* __restrict__ y, float* __restrict__ rowssq) {
  __shared__ f16 As[128][72];
  __shared__ f16 Bs[128][72];
  const int t = threadIdx.x;
  const int m0 = blockIdx.y * 128;  // local row within half
  const int n0 = blockIdx.x * 128;
  const int b = (m_base + m0) >> 12;
  const f16* Mb = M + (size_t)b * 65536;
  const int wave = t >> 6, lane = t & 63;
  const int wm = (wave >> 1) * 64, wn = (wave & 1) * 64;
  const int fr = lane & 15, fq = lane >> 4;
  f32x4 acc[4][4] = {};
#pragma unroll 1
  for (int kt = 0; kt < 4; ++kt) {
    const int k0 = kt * 64;
#pragma unroll
    for (int i = 0; i < 4; ++i) {
      int id = i * 256 + t;
      int row = id >> 3, cc = id & 7;
      *(f16x8*)&As[row][cc * 8] =
          cvt8(x + (size_t)(m_base + m0 + row) * 256 + k0 + cc * 8);
      *(uint4*)&Bs[row][cc * 8] =
          *(const uint4*)(Mb + (size_t)(n0 + row) * 256 + k0 + cc * 8);
    }
    __syncthreads();
#pragma unroll
    for (int ks = 0; ks < 2; ++ks) {
      f16x8 afr[4], bfr[4];
#pragma unroll
      for (int mi = 0; mi < 4; ++mi)
        afr[mi] = *(const f16x8*)&As[wm + mi * 16 + fr][ks * 32 + fq * 8];
#pragma unroll
      for (int ni = 0; ni < 4; ++ni)
        bfr[ni] = *(const f16x8*)&Bs[wn + ni * 16 + fr][ks * 32 + fq * 8];
#pragma unroll
      for (int mi = 0; mi < 4; ++mi)
#pragma unroll
        for (int ni = 0; ni < 4; ++ni)
          acc[mi][ni] = __builtin_amdgcn_mfma_f32_16x16x32_f16(
              afr[mi], bfr[ni], acc[mi][ni], 0, 0, 0);
    }
    __syncthreads();
  }
#pragma unroll
  for (int mi = 0; mi < 4; ++mi)
#pragma unroll
    for (int rr = 0; rr < 4; ++rr) {
      float s = 0.f;
#pragma unroll
      for (int ni = 0; ni < 4; ++ni) {
        float v = acc[mi][ni][rr];
        s += v * v;
        int row = m0 + wm + mi * 16 + fq * 4 + rr;
        int col = n0 + wn + ni * 16 + fr;
        y[(size_t)row * 256 + col] = (f16)v;
      }
#pragma unroll
      for (int off = 1; off < 16; off <<= 1) s += __shfl_xor(s, off);
      if (fr == 0)
        atomicAdd(&rowssq[m0 + wm + mi * 16 + fq * 4 + rr], s);
    }
}

// ---------------- out-GEMM: out = RMSNorm(y)*g @ Wo^T ----------------
__global__ __launch_bounds__(256) void ogemm_scaled(
    const f16* __restrict__ y, const float* __restrict__ rowssq,
    const float* __restrict__ g_rms, const float* __restrict__ Wo,
    float* __restrict__ out, int m_base) {
  __shared__ f16 As[128][72];
  __shared__ f16 Bs[128][72];
  const int t = threadIdx.x;
  const int m0 = blockIdx.y * 128;  // local row within half
  const int n0 = blockIdx.x * 128;
  const int wave = t >> 6, lane = t & 63;
  const int wm = (wave >> 1) * 64, wn = (wave & 1) * 64;
  const int fr = lane & 15, fq = lane >> 4;
  f32x4 acc[4][4] = {};
#pragma unroll 1
  for (int kt = 0; kt < 4; ++kt) {
    const int k0 = kt * 64;
#pragma unroll
    for (int i = 0; i < 4; ++i) {
      int id = i * 256 + t;
      int row = id >> 3, cc = id & 7;
      float rs = rsqrtf(rowssq[m0 + row] * (1.f / 256.f) + 1e-6f);
      const f16* yp = y + (size_t)(m0 + row) * 256 + k0 + cc * 8;
      const float* gp = g_rms + k0 + cc * 8;
      f16x8 a;
#pragma unroll
      for (int j = 0; j < 8; ++j) a[j] = (f16)((float)yp[j] * rs * gp[j]);
      *(f16x8*)&As[row][cc * 8] = a;
      *(f16x8*)&Bs[row][cc * 8] =
          cvt8(Wo + (size_t)(n0 + row) * 256 + k0 + cc * 8);
    }
    __syncthreads();
#pragma unroll
    for (int ks = 0; ks < 2; ++ks) {
      f16x8 afr[4], bfr[4];
#pragma unroll
      for (int mi = 0; mi < 4; ++mi)
        afr[mi] = *(const f16x8*)&As[wm + mi * 16 + fr][ks * 32 + fq * 8];
#pragma unroll
      for (int ni = 0; ni < 4; ++ni)
        bfr[ni] = *(const f16x8*)&Bs[wn + ni * 16 + fr][ks * 32 + fq * 8];
#pragma unroll
      for (int mi = 0; mi < 4; ++mi)
#pragma unroll
        for (int ni = 0; ni < 4; ++ni)
          acc[mi][ni] = __builtin_amdgcn_mfma_f32_16x16x32_f16(
              afr[mi], bfr[ni], acc[mi][ni], 0, 0, 0);
    }
    __syncthreads();
  }
#pragma unroll
  for (int mi = 0; mi < 4; ++mi)
#pragma unroll
    for (int ni = 0; ni < 4; ++ni)
#pragma unroll
      for (int rr = 0; rr < 4; ++rr) {
        int row = m_base + m0 + wm + mi * 16 + fq * 4 + rr;
        int col = n0 + wn + ni * 16 + fr;
        out[(size_t)row * 256 + col] = acc[mi][ni][rr];
      }
}

// ---------------- finalize S ----------------
// err = (Wv_h @ xbsum - 0.95*S @ kbsum)/4096 ; key = ksum/4096
// S_new = clip(0.95*S + outer(err, key), +-10)
__global__ __launch_bounds__(256) void finalize_S(
    const float* __restrict__ S, const float* __restrict__ Wv,
    const float* __restrict__ xbsum, const float* __restrict__ ksum,
    const float* __restrict__ kbsum, float* __restrict__ Sout) {
  const int bh = blockIdx.x;
  const int h = bh & 3;
  const int t = threadIdx.x;
  const int wave = t >> 6, lane = t & 63;
  __shared__ float xb[256], kb[64], key[64], errv[64];
  xb[t] = xbsum[bh * 256 + t];
  if (t < 64) {
    kb[t] = kbsum[bh * 64 + t];
    key[t] = ksum[bh * 64 + t] * (1.f / 4096.f);
  }
  __syncthreads();
#pragma unroll 1
  for (int ri = 0; ri < 16; ++ri) {
    int i = wave * 16 + ri;
    float4 wv4 = *(const float4*)(Wv + (size_t)(h * 64 + i) * 256 + lane * 4);
    float4 xb4 = *(const float4*)(&xb[lane * 4]);
    float s = wv4.x * xb4.x + wv4.y * xb4.y + wv4.z * xb4.z + wv4.w * xb4.w;
    s -= 0.95f * S[(size_t)bh * 4096 + i * 64 + lane] * kb[lane];
#pragma unroll
    for (int off = 32; off; off >>= 1) s += __shfl_xor(s, off);
    if (lane == 0) errv[i] = s * (1.f / 4096.f);
  }
  __syncthreads();
  for (int idx = t; idx < 4096; idx += 256) {
    int i = idx >> 6, j = idx & 63;
    float v = 0.95f * S[(size_t)bh * 4096 + idx] + errv[i] * key[j];
    Sout[(size_t)bh * 4096 + idx] = fminf(10.f, fmaxf(-10.f, v));
  }
}

extern "C" void kernel_launch(void* const* d_in, const int* in_sizes, int n_in,
                              void* d_out, int out_size, void* d_ws, size_t ws_size,
                              hipStream_t stream) {
  const float* x  = (const float*)d_in[0];
  const float* S  = (const float*)d_in[1];
  const float* Wq = (const float*)d_in[2];
  const float* Wk = (const float*)d_in[3];
  const float* Wv = (const float*)d_in[4];
  const float* Wb = (const float*)d_in[5];
  const float* Wo = (const float*)d_in[6];
  const float* g  = (const float*)d_in[7];

  char* w = (char*)d_ws;
  float* betaArr = (float*)w;                    // 1,048,576 B
  f16*   M       = (f16*)(w + 1048576);          // 2,097,152 B
  f16*   y       = (f16*)(w + 3145728);          // 16,777,216 B (32768x256)
  float* rowssq  = (float*)(w + 19922944);       // 262,144 B (2 halves)
  float* xbsum   = (float*)(w + 20185088);       // 65,536 B
  float* ksum    = (float*)(w + 20250624);       // 16,384 B
  float* kbsum   = (float*)(w + 20267008);       // 16,384 B

  float* out  = (float*)d_out;                   // [16,4096,256] fp32
  float* Sout = out + (size_t)16 * 4096 * 256;   // [16,4,64,64]  fp32

  hipMemsetAsync(w + 19922944, 0, 360448, stream);  // rowssq..kbsum
  beta_xbsum<<<1024, 256, 0, stream>>>(x, Wb, betaArr, xbsum);
  kgemm_sums<<<dim3(2, 512), 256, 0, stream>>>(x, Wk, betaArr, ksum, kbsum);
  fold_M<<<dim3(8, 64), 256, 0, stream>>>(S, Wq, M);
  for (int half = 0; half < 2; ++half) {
    int m_base = half * 32768;
    ygemm_ssq<<<dim3(2, 256), 256, 0, stream>>>(x, m_base, M, y,
                                                rowssq + half * 32768);
    ogemm_scaled<<<dim3(2, 256), 256, 0, stream>>>(y, rowssq + half * 32768, g,
                                                   Wo, out, m_base);
  }
  finalize_S<<<64, 256, 0, stream>>>(S, Wv, xbsum, ksum, kbsum, Sout);
}

// Round 5
// 235.834 us; speedup vs baseline: 1.4020x; 1.0629x over previous
//
#include <hip/hip_runtime.h>
#include <math.h>

// DeltaNetTemporal: B=16, N=4096, C=256, H=4, D=64.  All I/O fp32.
// R6: state_pass eliminated by linearity (fold+GEMM; v-GEMM eliminated).
// R7/R8: beta_xbsum latency fix: 330.6 -> 286.7 us.
// R9: fold_M re-parallelized (512 blocks, scalar S loads): 286.7 -> 250.7 us.
// R10: kgemm was staging-bound (MfmaUtil 5%, VALUBusy 23%, HBM 15% -- fp32
//   loads + cvt in every GEMM staging loop). Now x is converted to f16 ONCE
//   in beta_xbsum (xh, 32MB ws); Wk and Wo*g pre-converted by prep_w. All
//   GEMM staging is pure uint4 copies; ogemm applies RMS scale to f32
//   accumulators in the epilogue (g folded into Wo). Falls back to the R9
//   path if ws_size < 52MB.
// R11: identical resubmit of R10 (container-level bench failure, no
//   counters; audit found no OOB/race/misalignment; same precedent as R8).
// Pipeline: memset -> prep_w -> beta+xbsum(+xh) -> kGEMM -> fold M ->
//           2x[ yGEMM(+rowssq) -> outGEMM(rs in epilogue) ] -> finalize.

typedef _Float16 f16;
typedef f16 f16x8 __attribute__((ext_vector_type(8)));
typedef f16 f16x4 __attribute__((ext_vector_type(4)));
typedef float f32x4 __attribute__((ext_vector_type(4)));

__device__ __forceinline__ f16x8 cvt8(const float* q) {
  float4 a = *(const float4*)q;
  float4 b = *(const float4*)(q + 4);
  f16x8 r;
  r[0] = (f16)a.x; r[1] = (f16)a.y; r[2] = (f16)a.z; r[3] = (f16)a.w;
  r[4] = (f16)b.x; r[5] = (f16)b.y; r[6] = (f16)b.z; r[7] = (f16)b.w;
  return r;
}

// ---------------- prep: Wkh = f16(Wk); Wogh = f16(Wo * g) ----------------
__global__ __launch_bounds__(256) void prep_w(
    const float* __restrict__ Wk, const float* __restrict__ Wo,
    const float* __restrict__ g, f16* __restrict__ Wkh,
    f16* __restrict__ Wogh) {
  int i = blockIdx.x * 256 + threadIdx.x;  // grid 64 -> 16384 threads
#pragma unroll
  for (int j = 0; j < 4; ++j) {
    int idx = i + j * 16384;  // 65536 elements each
    Wkh[idx] = (f16)Wk[idx];
    Wogh[idx] = (f16)(Wo[idx] * g[idx & 255]);
  }
}

// ---------------- beta + xbsum (+ xh store) ----------------
// grid 1024: b = blk>>6, tile = blk&63 (64 rows/block, 16 rows/wave).
__global__ __launch_bounds__(256) void beta_xbsum_h(
    const float* __restrict__ x, const float* __restrict__ Wb,
    float* __restrict__ betaArr, float* __restrict__ xbsum,
    f16* __restrict__ xh) {
  const int t = threadIdx.x;
  const int wave = t >> 6, lane = t & 63;
  const int b = blockIdx.x >> 6;
  const int tile = blockIdx.x & 63;
  float4 wb[4];
#pragma unroll
  for (int h = 0; h < 4; ++h) wb[h] = *(const float4*)(Wb + h * 256 + lane * 4);
  float xacc[4][4] = {};
  const size_t rowbase = (size_t)b * 4096 + tile * 64;
  __shared__ float bsh[4][64];
  float4 xv = *(const float4*)(x + (rowbase + wave) * 256 + lane * 4);
#pragma unroll 2
  for (int i = 0; i < 16; ++i) {
    int r = i * 4 + wave;
    float4 nx = xv;
    if (i < 15)
      nx = *(const float4*)(x + (rowbase + r + 4) * 256 + lane * 4);
    // f16 copy of x (coalesced 8B/lane)
    f16x4 hx;
    hx[0] = (f16)xv.x; hx[1] = (f16)xv.y; hx[2] = (f16)xv.z; hx[3] = (f16)xv.w;
    *(f16x4*)(xh + (rowbase + r) * 256 + lane * 4) = hx;
#pragma unroll
    for (int h = 0; h < 4; ++h) {
      float s = xv.x * wb[h].x + xv.y * wb[h].y + xv.z * wb[h].z + xv.w * wb[h].w;
#pragma unroll
      for (int off = 32; off; off >>= 1) s += __shfl_xor(s, off);
      float bh = 1.f / (1.f + __expf(-s));
      if (lane == h) bsh[h][r] = bh;
      xacc[h][0] += bh * xv.x; xacc[h][1] += bh * xv.y;
      xacc[h][2] += bh * xv.z; xacc[h][3] += bh * xv.w;
    }
    xv = nx;
  }
  __shared__ float xbp[4][4][256];
#pragma unroll
  for (int h = 0; h < 4; ++h)
#pragma unroll
    for (int j = 0; j < 4; ++j) xbp[wave][h][lane * 4 + j] = xacc[h][j];
  __syncthreads();
  {
    int h = t >> 6, r = t & 63;
    betaArr[((size_t)(b * 4 + h) << 12) + tile * 64 + r] = bsh[h][r];
  }
  for (int idx = t; idx < 1024; idx += 256) {
    int h = idx >> 8, c = idx & 255;
    float s = xbp[0][h][c] + xbp[1][h][c] + xbp[2][h][c] + xbp[3][h][c];
    atomicAdd(&xbsum[(b * 4 + h) * 256 + c], s);
  }
}

// ---------------- k-GEMM (f16 inputs) with elu/L2norm/col-sum epilogue ----
__global__ __launch_bounds__(256) void kgemm_h(
    const f16* __restrict__ xh, const f16* __restrict__ Wkh,
    const float* __restrict__ betaArr,
    float* __restrict__ ksum, float* __restrict__ kbsum) {
  __shared__ union {
    struct { f16 A[128][72]; f16 B[128][72]; } s;
    f16 K[128][132];
  } u;
  __shared__ float bstage[2][128];
  const int t = threadIdx.x;
  const int m0 = blockIdx.y * 128;
  const int n0 = blockIdx.x * 128;
  const int b = m0 >> 12;
  const int wave = t >> 6, lane = t & 63;
  const int wm = (wave >> 1) * 64, wn = (wave & 1) * 64;
  const int fr = lane & 15, fq = lane >> 4;
  {
    int hh = t >> 7, r = t & 127;
    bstage[hh][r] =
        betaArr[((size_t)(b * 4 + (n0 >> 6) + hh) << 12) + (m0 & 4095) + r];
  }
  f32x4 acc[4][4] = {};
#pragma unroll 1
  for (int kt = 0; kt < 4; ++kt) {
    const int k0 = kt * 64;
#pragma unroll
    for (int i = 0; i < 4; ++i) {
      int id = i * 256 + t;
      int row = id >> 3, cc = id & 7;
      *(uint4*)&u.s.A[row][cc * 8] =
          *(const uint4*)(xh + (size_t)(m0 + row) * 256 + k0 + cc * 8);
      *(uint4*)&u.s.B[row][cc * 8] =
          *(const uint4*)(Wkh + (size_t)(n0 + row) * 256 + k0 + cc * 8);
    }
    __syncthreads();
#pragma unroll
    for (int ks = 0; ks < 2; ++ks) {
      f16x8 afr[4], bfr[4];
#pragma unroll
      for (int mi = 0; mi < 4; ++mi)
        afr[mi] = *(const f16x8*)&u.s.A[wm + mi * 16 + fr][ks * 32 + fq * 8];
#pragma unroll
      for (int ni = 0; ni < 4; ++ni)
        bfr[ni] = *(const f16x8*)&u.s.B[wn + ni * 16 + fr][ks * 32 + fq * 8];
#pragma unroll
      for (int mi = 0; mi < 4; ++mi)
#pragma unroll
        for (int ni = 0; ni < 4; ++ni)
          acc[mi][ni] = __builtin_amdgcn_mfma_f32_16x16x32_f16(
              afr[mi], bfr[ni], acc[mi][ni], 0, 0, 0);
    }
    __syncthreads();
  }
#pragma unroll
  for (int mi = 0; mi < 4; ++mi)
#pragma unroll
    for (int rr = 0; rr < 4; ++rr) {
      float s = 0.f;
#pragma unroll
      for (int ni = 0; ni < 4; ++ni) {
        float v = acc[mi][ni][rr];
        v = v > 0.f ? v + 1.f : __expf(v);
        acc[mi][ni][rr] = v;
        s += v * v;
      }
#pragma unroll
      for (int off = 1; off < 16; off <<= 1) s += __shfl_xor(s, off);
      float inv = 1.f / (sqrtf(s) + 1e-6f);
#pragma unroll
      for (int ni = 0; ni < 4; ++ni) acc[mi][ni][rr] *= inv;
    }
#pragma unroll
  for (int mi = 0; mi < 4; ++mi)
#pragma unroll
    for (int ni = 0; ni < 4; ++ni)
#pragma unroll
      for (int rr = 0; rr < 4; ++rr)
        u.K[wm + mi * 16 + fq * 4 + rr][wn + ni * 16 + fr] = (f16)acc[mi][ni][rr];
  __syncthreads();
  if (t < 128) {
    const int c = t, hl = c >> 6;
    float sk = 0.f, skb = 0.f;
#pragma unroll 4
    for (int r = 0; r < 128; ++r) {
      float v = (float)u.K[r][c];
      float be = bstage[hl][r];
      sk += v;
      skb += be * v;
    }
    int gh = b * 4 + (n0 >> 6) + hl;
    atomicAdd(&ksum[gh * 64 + (c & 63)], sk);
    atomicAdd(&kbsum[gh * 64 + (c & 63)], skb);
  }
}

// ---------------- fold: M[b][(h,d)][c] = 0.95 * S[b,h] @ Wq_h --------------
__global__ __launch_bounds__(256) void fold_M(
    const float* __restrict__ S, const float* __restrict__ Wq,
    f16* __restrict__ M) {
  const int bh = blockIdx.y;
  const int dq = blockIdx.x;
  const int h = bh & 3;
  const int t = threadIdx.x;
  const float* Sp = S + (size_t)bh * 4096 + dq * 8 * 64;
  const float* Wp = Wq + (size_t)h * 64 * 256 + t;
  float m[8] = {};
#pragma unroll 4
  for (int e = 0; e < 64; ++e) {
    float wv = Wp[e * 256];
#pragma unroll
    for (int dd = 0; dd < 8; ++dd) m[dd] += Sp[dd * 64 + e] * wv;
  }
  f16* Mb = M + (size_t)(bh >> 2) * 65536;
#pragma unroll
  for (int dd = 0; dd < 8; ++dd)
    Mb[(size_t)(h * 64 + dq * 8 + dd) * 256 + t] = (f16)(0.95f * m[dd]);
}

// ---------------- y-GEMM (f16 x): y = x @ M[b]^T + rowssq ----------------
__global__ __launch_bounds__(256) void ygemm_h(
    const f16* __restrict__ xh, int m_base, const f16* __restrict__ M,
    f16* __restrict__ y, float* __restrict__ rowssq) {
  __shared__ f16 As[128][72];
  __shared__ f16 Bs[128][72];
  const int t = threadIdx.x;
  const int m0 = blockIdx.y * 128;
  const int n0 = blockIdx.x * 128;
  const int b = (m_base + m0) >> 12;
  const f16* Mb = M + (size_t)b * 65536;
  const int wave = t >> 6, lane = t & 63;
  const int wm = (wave >> 1) * 64, wn = (wave & 1) * 64;
  const int fr = lane & 15, fq = lane >> 4;
  f32x4 acc[4][4] = {};
#pragma unroll 1
  for (int kt = 0; kt < 4; ++kt) {
    const int k0 = kt * 64;
#pragma unroll
    for (int i = 0; i < 4; ++i) {
      int id = i * 256 + t;
      int row = id >> 3, cc = id & 7;
      *(uint4*)&As[row][cc * 8] =
          *(const uint4*)(xh + (size_t)(m_base + m0 + row) * 256 + k0 + cc * 8);
      *(uint4*)&Bs[row][cc * 8] =
          *(const uint4*)(Mb + (size_t)(n0 + row) * 256 + k0 + cc * 8);
    }
    __syncthreads();
#pragma unroll
    for (int ks = 0; ks < 2; ++ks) {
      f16x8 afr[4], bfr[4];
#pragma unroll
      for (int mi = 0; mi < 4; ++mi)
        afr[mi] = *(const f16x8*)&As[wm + mi * 16 + fr][ks * 32 + fq * 8];
#pragma unroll
      for (int ni = 0; ni < 4; ++ni)
        bfr[ni] = *(const f16x8*)&Bs[wn + ni * 16 + fr][ks * 32 + fq * 8];
#pragma unroll
      for (int mi = 0; mi < 4; ++mi)
#pragma unroll
        for (int ni = 0; ni < 4; ++ni)
          acc[mi][ni] = __builtin_amdgcn_mfma_f32_16x16x32_f16(
              afr[mi], bfr[ni], acc[mi][ni], 0, 0, 0);
    }
    __syncthreads();
  }
#pragma unroll
  for (int mi = 0; mi < 4; ++mi)
#pragma unroll
    for (int rr = 0; rr < 4; ++rr) {
      float s = 0.f;
#pragma unroll
      for (int ni = 0; ni < 4; ++ni) {
        float v = acc[mi][ni][rr];
        s += v * v;
        int row = m0 + wm + mi * 16 + fq * 4 + rr;
        int col = n0 + wn + ni * 16 + fr;
        y[(size_t)row * 256 + col] = (f16)v;
      }
#pragma unroll
      for (int off = 1; off < 16; off <<= 1) s += __shfl_xor(s, off);
      if (fr == 0)
        atomicAdd(&rowssq[m0 + wm + mi * 16 + fq * 4 + rr], s);
    }
}

// ---------------- out-GEMM: out = rs[row] * (y @ (Wo*g)^T) ----------------
__global__ __launch_bounds__(256) void ogemm_h(
    const f16* __restrict__ y, const float* __restrict__ rowssq,
    const f16* __restrict__ Wogh, float* __restrict__ out, int m_base) {
  __shared__ f16 As[128][72];
  __shared__ f16 Bs[128][72];
  __shared__ float rsl[128];
  const int t = threadIdx.x;
  const int m0 = blockIdx.y * 128;
  const int n0 = blockIdx.x * 128;
  const int wave = t >> 6, lane = t & 63;
  const int wm = (wave >> 1) * 64, wn = (wave & 1) * 64;
  const int fr = lane & 15, fq = lane >> 4;
  if (t < 128) rsl[t] = rsqrtf(rowssq[m0 + t] * (1.f / 256.f) + 1e-6f);
  f32x4 acc[4][4] = {};
#pragma unroll 1
  for (int kt = 0; kt < 4; ++kt) {
    const int k0 = kt * 64;
#pragma unroll
    for (int i = 0; i < 4; ++i) {
      int id = i * 256 + t;
      int row = id >> 3, cc = id & 7;
      *(uint4*)&As[row][cc * 8] =
          *(const uint4*)(y + (size_t)(m0 + row) * 256 + k0 + cc * 8);
      *(uint4*)&Bs[row][cc * 8] =
          *(const uint4*)(Wogh + (size_t)(n0 + row) * 256 + k0 + cc * 8);
    }
    __syncthreads();
#pragma unroll
    for (int ks = 0; ks < 2; ++ks) {
      f16x8 afr[4], bfr[4];
#pragma unroll
      for (int mi = 0; mi < 4; ++mi)
        afr[mi] = *(const f16x8*)&As[wm + mi * 16 + fr][ks * 32 + fq * 8];
#pragma unroll
      for (int ni = 0; ni < 4; ++ni)
        bfr[ni] = *(const f16x8*)&Bs[wn + ni * 16 + fr][ks * 32 + fq * 8];
#pragma unroll
      for (int mi = 0; mi < 4; ++mi)
#pragma unroll
        for (int ni = 0; ni < 4; ++ni)
          acc[mi][ni] = __builtin_amdgcn_mfma_f32_16x16x32_f16(
              afr[mi], bfr[ni], acc[mi][ni], 0, 0, 0);
    }
    __syncthreads();
  }
#pragma unroll
  for (int mi = 0; mi < 4; ++mi)
#pragma unroll
    for (int rr = 0; rr < 4; ++rr) {
      int lrow = wm + mi * 16 + fq * 4 + rr;
      float rs = rsl[lrow];
#pragma unroll
      for (int ni = 0; ni < 4; ++ni) {
        int row = m_base + m0 + lrow;
        int col = n0 + wn + ni * 16 + fr;
        out[(size_t)row * 256 + col] = rs * acc[mi][ni][rr];
      }
    }
}

// ================= R9 fallback path (fp32 staging) =================
__global__ __launch_bounds__(256) void beta_xbsum(
    const float* __restrict__ x, const float* __restrict__ Wb,
    float* __restrict__ betaArr, float* __restrict__ xbsum) {
  const int t = threadIdx.x;
  const int wave = t >> 6, lane = t & 63;
  const int b = blockIdx.x >> 6;
  const int tile = blockIdx.x & 63;
  float4 wb[4];
#pragma unroll
  for (int h = 0; h < 4; ++h) wb[h] = *(const float4*)(Wb + h * 256 + lane * 4);
  float xacc[4][4] = {};
  const size_t rowbase = (size_t)b * 4096 + tile * 64;
  __shared__ float bsh[4][64];
  float4 xv = *(const float4*)(x + (rowbase + wave) * 256 + lane * 4);
#pragma unroll 2
  for (int i = 0; i < 16; ++i) {
    int r = i * 4 + wave;
    float4 nx = xv;
    if (i < 15)
      nx = *(const float4*)(x + (rowbase + r + 4) * 256 + lane * 4);
#pragma unroll
    for (int h = 0; h < 4; ++h) {
      float s = xv.x * wb[h].x + xv.y * wb[h].y + xv.z * wb[h].z + xv.w * wb[h].w;
#pragma unroll
      for (int off = 32; off; off >>= 1) s += __shfl_xor(s, off);
      float bh = 1.f / (1.f + __expf(-s));
      if (lane == h) bsh[h][r] = bh;
      xacc[h][0] += bh * xv.x; xacc[h][1] += bh * xv.y;
      xacc[h][2] += bh * xv.z; xacc[h][3] += bh * xv.w;
    }
    xv = nx;
  }
  __shared__ float xbp[4][4][256];
#pragma unroll
  for (int h = 0; h < 4; ++h)
#pragma unroll
    for (int j = 0; j < 4; ++j) xbp[wave][h][lane * 4 + j] = xacc[h][j];
  __syncthreads();
  {
    int h = t >> 6, r = t & 63;
    betaArr[((size_t)(b * 4 + h) << 12) + tile * 64 + r] = bsh[h][r];
  }
  for (int idx = t; idx < 1024; idx += 256) {
    int h = idx >> 8, c = idx & 255;
    float s = xbp[0][h][c] + xbp[1][h][c] + xbp[2][h][c] + xbp[3][h][c];
    atomicAdd(&xbsum[(b * 4 + h) * 256 + c], s);
  }
}

__global__ __launch_bounds__(256) void kgemm_sums(
    const float* __restrict__ x, const float* __restrict__ Wk,
    const float* __restrict__ betaArr,
    float* __restrict__ ksum, float* __restrict__ kbsum) {
  __shared__ union {
    struct { f16 A[128][72]; f16 B[128][72]; } s;
    f16 K[128][132];
  } u;
  __shared__ float bstage[2][128];
  const int t = threadIdx.x;
  const int m0 = blockIdx.y * 128;
  const int n0 = blockIdx.x * 128;
  const int b = m0 >> 12;
  const int wave = t >> 6, lane = t & 63;
  const int wm = (wave >> 1) * 64, wn = (wave & 1) * 64;
  const int fr = lane & 15, fq = lane >> 4;
  {
    int hh = t >> 7, r = t & 127;
    bstage[hh][r] =
        betaArr[((size_t)(b * 4 + (n0 >> 6) + hh) << 12) + (m0 & 4095) + r];
  }
  f32x4 acc[4][4] = {};
#pragma unroll 1
  for (int kt = 0; kt < 4; ++kt) {
    const int k0 = kt * 64;
#pragma unroll
    for (int i = 0; i < 4; ++i) {
      int id = i * 256 + t;
      int row = id >> 3, cc = id & 7;
      *(f16x8*)&u.s.A[row][cc * 8] =
          cvt8(x + (size_t)(m0 + row) * 256 + k0 + cc * 8);
      *(f16x8*)&u.s.B[row][cc * 8] =
          cvt8(Wk + (size_t)(n0 + row) * 256 + k0 + cc * 8);
    }
    __syncthreads();
#pragma unroll
    for (int ks = 0; ks < 2; ++ks) {
      f16x8 afr[4], bfr[4];
#pragma unroll
      for (int mi = 0; mi < 4; ++mi)
        afr[mi] = *(const f16x8*)&u.s.A[wm + mi * 16 + fr][ks * 32 + fq * 8];
#pragma unroll
      for (int ni = 0; ni < 4; ++ni)
        bfr[ni] = *(const f16x8*)&u.s.B[wn + ni * 16 + fr][ks * 32 + fq * 8];
#pragma unroll
      for (int mi = 0; mi < 4; ++mi)
#pragma unroll
        for (int ni = 0; ni < 4; ++ni)
          acc[mi][ni] = __builtin_amdgcn_mfma_f32_16x16x32_f16(
              afr[mi], bfr[ni], acc[mi][ni], 0, 0, 0);
    }
    __syncthreads();
  }
#pragma unroll
  for (int mi = 0; mi < 4; ++mi)
#pragma unroll
    for (int rr = 0; rr < 4; ++rr) {
      float s = 0.f;
#pragma unroll
      for (int ni = 0; ni < 4; ++ni) {
        float v = acc[mi][ni][rr];
        v = v > 0.f ? v + 1.f : __expf(v);
        acc[mi][ni][rr] = v;
        s += v * v;
      }
#pragma unroll
      for (int off = 1; off < 16; off <<= 1) s += __shfl_xor(s, off);
      float inv = 1.f / (sqrtf(s) + 1e-6f);
#pragma unroll
      for (int ni = 0; ni < 4; ++ni) acc[mi][ni][rr] *= inv;
    }
#pragma unroll
  for (int mi = 0; mi < 4; ++mi)
#pragma unroll
    for (int ni = 0; ni < 4; ++ni)
#pragma unroll
      for (int rr = 0; rr < 4; ++rr)
        u.K[wm + mi * 16 + fq * 4 + rr][wn + ni * 16 + fr] = (f16)acc[mi][ni][rr];
  __syncthreads();
  if (t < 128) {
    const int c = t, hl = c >> 6;
    float sk = 0.f, skb = 0.f;
#pragma unroll 4
    for (int r = 0; r < 128; ++r) {
      float v = (float)u.K[r][c];
      float be = bstage[hl][r];
      sk += v;
      skb += be * v;
    }
    int gh = b * 4 + (n0 >> 6) + hl;
    atomicAdd(&ksum[gh * 64 + (c & 63)], sk);
    atomicAdd(&kbsum[gh * 64 + (c & 63)], skb);
  }
}

__global__ __launch_bounds__(256) void ygemm_ssq(
    const float* __restrict__ x, int m_base, const f16* __restrict__ M,
    f16* __restrict__ y, float* __restrict__ rowssq) {
  __shared__ f16 As[128][72];
  __shared__ f16 Bs[128][72];
  const int t = threadIdx.x;
  const int m0 = blockIdx.y * 128;
  const int n0 = blockIdx.x * 128;
  const int b = (m_base + m0) >> 12;
  const f16* Mb = M + (size_t)b * 65536;
  const int wave = t >> 6, lane = t & 63;
  const int wm = (wave >> 1) * 64, wn = (wave & 1) * 64;
  const int fr = lane & 15, fq = lane >> 4;
  f32x4 acc[4][4] = {};
#pragma unroll 1
  for (int kt = 0; kt < 4; ++kt) {
    const int k0 = kt * 64;
#pragma unroll
    for (int i = 0; i < 4; ++i) {
      int id = i * 256 + t;
      int row = id >> 3, cc = id & 7;
      *(f16x8*)&As[row][cc * 8] =
          cvt8(x + (size_t)(m_base + m0 + row) * 256 + k0 + cc * 8);
      *(uint4*)&Bs[row][cc * 8] =
          *(const uint4*)(Mb + (size_t)(n0 + row) * 256 + k0 + cc * 8);
    }
    __syncthreads();
#pragma unroll
    for (int ks = 0; ks < 2; ++ks) {
      f16x8 afr[4], bfr[4];
#pragma unroll
      for (int mi = 0; mi < 4; ++mi)
        afr[mi] = *(const f16x8*)&As[wm + mi * 16 + fr][ks * 32 + fq * 8];
#pragma unroll
      for (int ni = 0; ni < 4; ++ni)
        bfr[ni] = *(const f16x8*)&Bs[wn + ni * 16 + fr][ks * 32 + fq * 8];
#pragma unroll
      for (int mi = 0; mi < 4; ++mi)
#pragma unroll
        for (int ni = 0; ni < 4; ++ni)
          acc[mi][ni] = __builtin_amdgcn_mfma_f32_16x16x32_f16(
              afr[mi], bfr[ni], acc[mi][ni], 0, 0, 0);
    }
    __syncthreads();
  }
#pragma unroll
  for (int mi = 0; mi < 4; ++mi)
#pragma unroll
    for (int rr = 0; rr < 4; ++rr) {
      float s = 0.f;
#pragma unroll
      for (int ni = 0; ni < 4; ++ni) {
        float v = acc[mi][ni][rr];
        s += v * v;
        int row = m0 + wm + mi * 16 + fq * 4 + rr;
        int col = n0 + wn + ni * 16 + fr;
        y[(size_t)row * 256 + col] = (f16)v;
      }
#pragma unroll
      for (int off = 1; off < 16; off <<= 1) s += __shfl_xor(s, off);
      if (fr == 0)
        atomicAdd(&rowssq[m0 + wm + mi * 16 + fq * 4 + rr], s);
    }
}

__global__ __launch_bounds__(256) void ogemm_scaled(
    const f16* __restrict__ y, const float* __restrict__ rowssq,
    const float* __restrict__ g_rms, const float* __restrict__ Wo,
    float* __restrict__ out, int m_base) {
  __shared__ f16 As[128][72];
  __shared__ f16 Bs[128][72];
  const int t = threadIdx.x;
  const int m0 = blockIdx.y * 128;
  const int n0 = blockIdx.x * 128;
  const int wave = t >> 6, lane = t & 63;
  const int wm = (wave >> 1) * 64, wn = (wave & 1) * 64;
  const int fr = lane & 15, fq = lane >> 4;
  f32x4 acc[4][4] = {};
#pragma unroll 1
  for (int kt = 0; kt < 4; ++kt) {
    const int k0 = kt * 64;
#pragma unroll
    for (int i = 0; i < 4; ++i) {
      int id = i * 256 + t;
      int row = id >> 3, cc = id & 7;
      float rs = rsqrtf(rowssq[m0 + row] * (1.f / 256.f) + 1e-6f);
      const f16* yp = y + (size_t)(m0 + row) * 256 + k0 + cc * 8;
      const float* gp = g_rms + k0 + cc * 8;
      f16x8 a;
#pragma unroll
      for (int j = 0; j < 8; ++j) a[j] = (f16)((float)yp[j] * rs * gp[j]);
      *(f16x8*)&As[row][cc * 8] = a;
      *(f16x8*)&Bs[row][cc * 8] =
          cvt8(Wo + (size_t)(n0 + row) * 256 + k0 + cc * 8);
    }
    __syncthreads();
#pragma unroll
    for (int ks = 0; ks < 2; ++ks) {
      f16x8 afr[4], bfr[4];
#pragma unroll
      for (int mi = 0; mi < 4; ++mi)
        afr[mi] = *(const f16x8*)&As[wm + mi * 16 + fr][ks * 32 + fq * 8];
#pragma unroll
      for (int ni = 0; ni < 4; ++ni)
        bfr[ni] = *(const f16x8*)&Bs[wn + ni * 16 + fr][ks * 32 + fq * 8];
#pragma unroll
      for (int mi = 0; mi < 4; ++mi)
#pragma unroll
        for (int ni = 0; ni < 4; ++ni)
          acc[mi][ni] = __builtin_amdgcn_mfma_f32_16x16x32_f16(
              afr[mi], bfr[ni], acc[mi][ni], 0, 0, 0);
    }
    __syncthreads();
  }
#pragma unroll
  for (int mi = 0; mi < 4; ++mi)
#pragma unroll
    for (int ni = 0; ni < 4; ++ni)
#pragma unroll
      for (int rr = 0; rr < 4; ++rr) {
        int row = m_base + m0 + wm + mi * 16 + fq * 4 + rr;
        int col = n0 + wn + ni * 16 + fr;
        out[(size_t)row * 256 + col] = acc[mi][ni][rr];
      }
}

// ---------------- finalize S ----------------
__global__ __launch_bounds__(256) void finalize_S(
    const float* __restrict__ S, const float* __restrict__ Wv,
    const float* __restrict__ xbsum, const float* __restrict__ ksum,
    const float* __restrict__ kbsum, float* __restrict__ Sout) {
  const int bh = blockIdx.x;
  const int h = bh & 3;
  const int t = threadIdx.x;
  const int wave = t >> 6, lane = t & 63;
  __shared__ float xb[256], kb[64], key[64], errv[64];
  xb[t] = xbsum[bh * 256 + t];
  if (t < 64) {
    kb[t] = kbsum[bh * 64 + t];
    key[t] = ksum[bh * 64 + t] * (1.f / 4096.f);
  }
  __syncthreads();
#pragma unroll 1
  for (int ri = 0; ri < 16; ++ri) {
    int i = wave * 16 + ri;
    float4 wv4 = *(const float4*)(Wv + (size_t)(h * 64 + i) * 256 + lane * 4);
    float4 xb4 = *(const float4*)(&xb[lane * 4]);
    float s = wv4.x * xb4.x + wv4.y * xb4.y + wv4.z * xb4.z + wv4.w * xb4.w;
    s -= 0.95f * S[(size_t)bh * 4096 + i * 64 + lane] * kb[lane];
#pragma unroll
    for (int off = 32; off; off >>= 1) s += __shfl_xor(s, off);
    if (lane == 0) errv[i] = s * (1.f / 4096.f);
  }
  __syncthreads();
  for (int idx = t; idx < 4096; idx += 256) {
    int i = idx >> 6, j = idx & 63;
    float v = 0.95f * S[(size_t)bh * 4096 + idx] + errv[i] * key[j];
    Sout[(size_t)bh * 4096 + idx] = fminf(10.f, fmaxf(-10.f, v));
  }
}

extern "C" void kernel_launch(void* const* d_in, const int* in_sizes, int n_in,
                              void* d_out, int out_size, void* d_ws, size_t ws_size,
                              hipStream_t stream) {
  const float* x  = (const float*)d_in[0];
  const float* S  = (const float*)d_in[1];
  const float* Wq = (const float*)d_in[2];
  const float* Wk = (const float*)d_in[3];
  const float* Wv = (const float*)d_in[4];
  const float* Wb = (const float*)d_in[5];
  const float* Wo = (const float*)d_in[6];
  const float* g  = (const float*)d_in[7];

  char* w = (char*)d_ws;
  float* betaArr = (float*)w;                    // 1,048,576 B
  f16*   M       = (f16*)(w + 1048576);          // 2,097,152 B
  f16*   y       = (f16*)(w + 3145728);          // 16,777,216 B (32768x256)
  float* rowssq  = (float*)(w + 19922944);       // 262,144 B (2 halves)
  float* xbsum   = (float*)(w + 20185088);       // 65,536 B
  float* ksum    = (float*)(w + 20250624);       // 16,384 B
  float* kbsum   = (float*)(w + 20267008);       // 16,384 B
  // R10 extension
  f16*   xh      = (f16*)(w + 20283392);         // 33,554,432 B (65536x256)
  f16*   Wkh     = (f16*)(w + 53837824);         // 131,072 B
  f16*   Wogh    = (f16*)(w + 53968896);         // 131,072 B
  const size_t WS_NEED = 54099968ull;

  float* out  = (float*)d_out;                   // [16,4096,256] fp32
  float* Sout = out + (size_t)16 * 4096 * 256;   // [16,4,64,64]  fp32

  hipMemsetAsync(w + 19922944, 0, 360448, stream);  // rowssq..kbsum

  if (ws_size >= WS_NEED) {
    prep_w<<<64, 256, 0, stream>>>(Wk, Wo, g, Wkh, Wogh);
    beta_xbsum_h<<<1024, 256, 0, stream>>>(x, Wb, betaArr, xbsum, xh);
    kgemm_h<<<dim3(2, 512), 256, 0, stream>>>(xh, Wkh, betaArr, ksum, kbsum);
    fold_M<<<dim3(8, 64), 256, 0, stream>>>(S, Wq, M);
    for (int half = 0; half < 2; ++half) {
      int m_base = half * 32768;
      ygemm_h<<<dim3(2, 256), 256, 0, stream>>>(xh, m_base, M, y,
                                                rowssq + half * 32768);
      ogemm_h<<<dim3(2, 256), 256, 0, stream>>>(y, rowssq + half * 32768,
                                                Wogh, out, m_base);
    }
  } else {
    beta_xbsum<<<1024, 256, 0, stream>>>(x, Wb, betaArr, xbsum);
    kgemm_sums<<<dim3(2, 512), 256, 0, stream>>>(x, Wk, betaArr, ksum, kbsum);
    fold_M<<<dim3(8, 64), 256, 0, stream>>>(S, Wq, M);
    for (int half = 0; half < 2; ++half) {
      int m_base = half * 32768;
      ygemm_ssq<<<dim3(2, 256), 256, 0, stream>>>(x, m_base, M, y,
                                                  rowssq + half * 32768);
      ogemm_scaled<<<dim3(2, 256), 256, 0, stream>>>(y, rowssq + half * 32768,
                                                     g, Wo, out, m_base);
    }
  }
  finalize_S<<<64, 256, 0, stream>>>(S, Wv, xbsum, ksum, kbsum, Sout);
}

// Round 6
// 234.966 us; speedup vs baseline: 1.4072x; 1.0037x over previous
//
#include <hip/hip_runtime.h>
#include <math.h>

// DeltaNetTemporal: B=16, N=4096, C=256, H=4, D=64.  All I/O fp32.
// R6: state_pass eliminated by linearity (fold+GEMM; v-GEMM eliminated).
// R7/R8: beta_xbsum latency fix: 330.6 -> 286.7 us.
// R9: fold_M re-parallelized: 286.7 -> 250.7 us.
// R10/R11: f16 pre-conversion of x/Wk/Wo*g; pure-copy staging: 250.7 -> 235.8.
// R12: GEMM staging via __builtin_amdgcn_global_load_lds width=16 (removes
//   global->VGPR->ds_write round trip; m151: +35% at 128^2 tile). gload_lds
//   needs linear LDS dest -> unpadded [128][64] tiles with m201-style
//   both-sides swizzle: source 16B-chunk XOR'd by row&7 at stage, ds_read at
//   chunk (ks*4+fq)^(fr&7). Bank cost unchanged vs padded (8-lane groups =
//   b128 structural floor). kgemm K-tile pitch 132->128 (union = exactly 32KB).
// Pipeline: memset -> prep_w -> beta+xbsum(+xh) -> kGEMM -> fold M ->
//           2x[ yGEMM(+rowssq) -> outGEMM(rs in epilogue) ] -> finalize.

typedef _Float16 f16;
typedef f16 f16x8 __attribute__((ext_vector_type(8)));
typedef f16 f16x4 __attribute__((ext_vector_type(4)));
typedef float f32x4 __attribute__((ext_vector_type(4)));

typedef const __attribute__((address_space(1))) void gvoid;
typedef __attribute__((address_space(3))) void svoid;

// async global->LDS, 16B/lane; LDS dest is wave-uniform base + lane*16.
__device__ __forceinline__ void gload16(const void* g, void* l) {
  __builtin_amdgcn_global_load_lds((gvoid*)g, (svoid*)l, 16, 0, 0);
}

__device__ __forceinline__ f16x8 cvt8(const float* q) {
  float4 a = *(const float4*)q;
  float4 b = *(const float4*)(q + 4);
  f16x8 r;
  r[0] = (f16)a.x; r[1] = (f16)a.y; r[2] = (f16)a.z; r[3] = (f16)a.w;
  r[4] = (f16)b.x; r[5] = (f16)b.y; r[6] = (f16)b.z; r[7] = (f16)b.w;
  return r;
}

// ---------------- prep: Wkh = f16(Wk); Wogh = f16(Wo * g) ----------------
__global__ __launch_bounds__(256) void prep_w(
    const float* __restrict__ Wk, const float* __restrict__ Wo,
    const float* __restrict__ g, f16* __restrict__ Wkh,
    f16* __restrict__ Wogh) {
  int i = blockIdx.x * 256 + threadIdx.x;  // grid 64 -> 16384 threads
#pragma unroll
  for (int j = 0; j < 4; ++j) {
    int idx = i + j * 16384;  // 65536 elements each
    Wkh[idx] = (f16)Wk[idx];
    Wogh[idx] = (f16)(Wo[idx] * g[idx & 255]);
  }
}

// ---------------- beta + xbsum (+ xh store) ----------------
// grid 1024: b = blk>>6, tile = blk&63 (64 rows/block, 16 rows/wave).
__global__ __launch_bounds__(256) void beta_xbsum_h(
    const float* __restrict__ x, const float* __restrict__ Wb,
    float* __restrict__ betaArr, float* __restrict__ xbsum,
    f16* __restrict__ xh) {
  const int t = threadIdx.x;
  const int wave = t >> 6, lane = t & 63;
  const int b = blockIdx.x >> 6;
  const int tile = blockIdx.x & 63;
  float4 wb[4];
#pragma unroll
  for (int h = 0; h < 4; ++h) wb[h] = *(const float4*)(Wb + h * 256 + lane * 4);
  float xacc[4][4] = {};
  const size_t rowbase = (size_t)b * 4096 + tile * 64;
  __shared__ float bsh[4][64];
  float4 xv = *(const float4*)(x + (rowbase + wave) * 256 + lane * 4);
#pragma unroll 2
  for (int i = 0; i < 16; ++i) {
    int r = i * 4 + wave;
    float4 nx = xv;
    if (i < 15)
      nx = *(const float4*)(x + (rowbase + r + 4) * 256 + lane * 4);
    f16x4 hx;
    hx[0] = (f16)xv.x; hx[1] = (f16)xv.y; hx[2] = (f16)xv.z; hx[3] = (f16)xv.w;
    *(f16x4*)(xh + (rowbase + r) * 256 + lane * 4) = hx;
#pragma unroll
    for (int h = 0; h < 4; ++h) {
      float s = xv.x * wb[h].x + xv.y * wb[h].y + xv.z * wb[h].z + xv.w * wb[h].w;
#pragma unroll
      for (int off = 32; off; off >>= 1) s += __shfl_xor(s, off);
      float bh = 1.f / (1.f + __expf(-s));
      if (lane == h) bsh[h][r] = bh;
      xacc[h][0] += bh * xv.x; xacc[h][1] += bh * xv.y;
      xacc[h][2] += bh * xv.z; xacc[h][3] += bh * xv.w;
    }
    xv = nx;
  }
  __shared__ float xbp[4][4][256];
#pragma unroll
  for (int h = 0; h < 4; ++h)
#pragma unroll
    for (int j = 0; j < 4; ++j) xbp[wave][h][lane * 4 + j] = xacc[h][j];
  __syncthreads();
  {
    int h = t >> 6, r = t & 63;
    betaArr[((size_t)(b * 4 + h) << 12) + tile * 64 + r] = bsh[h][r];
  }
  for (int idx = t; idx < 1024; idx += 256) {
    int h = idx >> 8, c = idx & 255;
    float s = xbp[0][h][c] + xbp[1][h][c] + xbp[2][h][c] + xbp[3][h][c];
    atomicAdd(&xbsum[(b * 4 + h) * 256 + c], s);
  }
}

// ---------------- k-GEMM (gload_lds staging) + elu/L2norm/col-sums --------
__global__ __launch_bounds__(256) void kgemm_h(
    const f16* __restrict__ xh, const f16* __restrict__ Wkh,
    const float* __restrict__ betaArr,
    float* __restrict__ ksum, float* __restrict__ kbsum) {
  __shared__ union {
    struct { f16 A[128][64]; f16 B[128][64]; } s;  // 32 KB staging
    f16 K[128][128];                               // 32 KB epilogue tile
  } u;
  __shared__ float bstage[2][128];
  const int t = threadIdx.x;
  const int m0 = blockIdx.y * 128;
  const int n0 = blockIdx.x * 128;
  const int b = m0 >> 12;
  const int wave = t >> 6, lane = t & 63;
  const int wm = (wave >> 1) * 64, wn = (wave & 1) * 64;
  const int fr = lane & 15, fq = lane >> 4;
  const int fr7 = fr & 7;
  // staging geometry: chunk c = 8 rows x 64 f16; lane covers row c*8+(lane>>3),
  // source 16B-chunk sc = (lane&7) ^ (row&7)  [both-sides swizzle]
  const int srow = lane >> 3;
  const int sc = (lane & 7) ^ srow;
  {
    int hh = t >> 7, r = t & 127;
    bstage[hh][r] =
        betaArr[((size_t)(b * 4 + (n0 >> 6) + hh) << 12) + (m0 & 4095) + r];
  }
  const char* Ab = (const char*)&u.s.A[0][0];
  const char* Bb = (const char*)&u.s.B[0][0];
  f32x4 acc[4][4] = {};
#pragma unroll 1
  for (int kt = 0; kt < 4; ++kt) {
    const int k0 = kt * 64;
#pragma unroll
    for (int j = 0; j < 4; ++j) {
      int c = j * 4 + wave;
      int row = c * 8 + srow;
      gload16(xh + (size_t)(m0 + row) * 256 + k0 + sc * 8, &u.s.A[0][0] + c * 512);
      gload16(Wkh + (size_t)(n0 + row) * 256 + k0 + sc * 8, &u.s.B[0][0] + c * 512);
    }
    __syncthreads();
#pragma unroll
    for (int ks = 0; ks < 2; ++ks) {
      const int p = ((ks * 4 + fq) ^ fr7) << 4;
      f16x8 afr[4], bfr[4];
#pragma unroll
      for (int mi = 0; mi < 4; ++mi)
        afr[mi] = *(const f16x8*)(Ab + (wm + mi * 16 + fr) * 128 + p);
#pragma unroll
      for (int ni = 0; ni < 4; ++ni)
        bfr[ni] = *(const f16x8*)(Bb + (wn + ni * 16 + fr) * 128 + p);
#pragma unroll
      for (int mi = 0; mi < 4; ++mi)
#pragma unroll
        for (int ni = 0; ni < 4; ++ni)
          acc[mi][ni] = __builtin_amdgcn_mfma_f32_16x16x32_f16(
              afr[mi], bfr[ni], acc[mi][ni], 0, 0, 0);
    }
    __syncthreads();
  }
  // elu+1, L2-normalize per (row, head) — head == this wave's 64-col range.
#pragma unroll
  for (int mi = 0; mi < 4; ++mi)
#pragma unroll
    for (int rr = 0; rr < 4; ++rr) {
      float s = 0.f;
#pragma unroll
      for (int ni = 0; ni < 4; ++ni) {
        float v = acc[mi][ni][rr];
        v = v > 0.f ? v + 1.f : __expf(v);
        acc[mi][ni][rr] = v;
        s += v * v;
      }
#pragma unroll
      for (int off = 1; off < 16; off <<= 1) s += __shfl_xor(s, off);
      float inv = 1.f / (sqrtf(s) + 1e-6f);
#pragma unroll
      for (int ni = 0; ni < 4; ++ni) acc[mi][ni][rr] *= inv;
    }
  // k' -> LDS (aliases staging; all waves past final barrier)
#pragma unroll
  for (int mi = 0; mi < 4; ++mi)
#pragma unroll
    for (int ni = 0; ni < 4; ++ni)
#pragma unroll
      for (int rr = 0; rr < 4; ++rr)
        u.K[wm + mi * 16 + fq * 4 + rr][wn + ni * 16 + fr] = (f16)acc[mi][ni][rr];
  __syncthreads();
  if (t < 128) {
    const int c = t, hl = c >> 6;
    float sk = 0.f, skb = 0.f;
#pragma unroll 4
    for (int r = 0; r < 128; ++r) {
      float v = (float)u.K[r][c];
      float be = bstage[hl][r];
      sk += v;
      skb += be * v;
    }
    int gh = b * 4 + (n0 >> 6) + hl;
    atomicAdd(&ksum[gh * 64 + (c & 63)], sk);
    atomicAdd(&kbsum[gh * 64 + (c & 63)], skb);
  }
}

// ---------------- fold: M[b][(h,d)][c] = 0.95 * S[b,h] @ Wq_h --------------
__global__ __launch_bounds__(256) void fold_M(
    const float* __restrict__ S, const float* __restrict__ Wq,
    f16* __restrict__ M) {
  const int bh = blockIdx.y;
  const int dq = blockIdx.x;
  const int h = bh & 3;
  const int t = threadIdx.x;
  const float* Sp = S + (size_t)bh * 4096 + dq * 8 * 64;
  const float* Wp = Wq + (size_t)h * 64 * 256 + t;
  float m[8] = {};
#pragma unroll 4
  for (int e = 0; e < 64; ++e) {
    float wv = Wp[e * 256];
#pragma unroll
    for (int dd = 0; dd < 8; ++dd) m[dd] += Sp[dd * 64 + e] * wv;
  }
  f16* Mb = M + (size_t)(bh >> 2) * 65536;
#pragma unroll
  for (int dd = 0; dd < 8; ++dd)
    Mb[(size_t)(h * 64 + dq * 8 + dd) * 256 + t] = (f16)(0.95f * m[dd]);
}

// ---------------- y-GEMM (gload_lds): y = x @ M[b]^T + rowssq -------------
__global__ __launch_bounds__(256) void ygemm_h(
    const f16* __restrict__ xh, int m_base, const f16* __restrict__ M,
    f16* __restrict__ y, float* __restrict__ rowssq) {
  __shared__ f16 As[128][64];
  __shared__ f16 Bs[128][64];
  const int t = threadIdx.x;
  const int m0 = blockIdx.y * 128;
  const int n0 = blockIdx.x * 128;
  const int b = (m_base + m0) >> 12;
  const f16* Mb = M + (size_t)b * 65536;
  const int wave = t >> 6, lane = t & 63;
  const int wm = (wave >> 1) * 64, wn = (wave & 1) * 64;
  const int fr = lane & 15, fq = lane >> 4;
  const int fr7 = fr & 7;
  const int srow = lane >> 3;
  const int sc = (lane & 7) ^ srow;
  const char* Ab = (const char*)&As[0][0];
  const char* Bb = (const char*)&Bs[0][0];
  f32x4 acc[4][4] = {};
#pragma unroll 1
  for (int kt = 0; kt < 4; ++kt) {
    const int k0 = kt * 64;
#pragma unroll
    for (int j = 0; j < 4; ++j) {
      int c = j * 4 + wave;
      int row = c * 8 + srow;
      gload16(xh + (size_t)(m_base + m0 + row) * 256 + k0 + sc * 8,
              &As[0][0] + c * 512);
      gload16(Mb + (size_t)(n0 + row) * 256 + k0 + sc * 8, &Bs[0][0] + c * 512);
    }
    __syncthreads();
#pragma unroll
    for (int ks = 0; ks < 2; ++ks) {
      const int p = ((ks * 4 + fq) ^ fr7) << 4;
      f16x8 afr[4], bfr[4];
#pragma unroll
      for (int mi = 0; mi < 4; ++mi)
        afr[mi] = *(const f16x8*)(Ab + (wm + mi * 16 + fr) * 128 + p);
#pragma unroll
      for (int ni = 0; ni < 4; ++ni)
        bfr[ni] = *(const f16x8*)(Bb + (wn + ni * 16 + fr) * 128 + p);
#pragma unroll
      for (int mi = 0; mi < 4; ++mi)
#pragma unroll
        for (int ni = 0; ni < 4; ++ni)
          acc[mi][ni] = __builtin_amdgcn_mfma_f32_16x16x32_f16(
              afr[mi], bfr[ni], acc[mi][ni], 0, 0, 0);
    }
    __syncthreads();
  }
#pragma unroll
  for (int mi = 0; mi < 4; ++mi)
#pragma unroll
    for (int rr = 0; rr < 4; ++rr) {
      float s = 0.f;
#pragma unroll
      for (int ni = 0; ni < 4; ++ni) {
        float v = acc[mi][ni][rr];
        s += v * v;
        int row = m0 + wm + mi * 16 + fq * 4 + rr;
        int col = n0 + wn + ni * 16 + fr;
        y[(size_t)row * 256 + col] = (f16)v;
      }
#pragma unroll
      for (int off = 1; off < 16; off <<= 1) s += __shfl_xor(s, off);
      if (fr == 0)
        atomicAdd(&rowssq[m0 + wm + mi * 16 + fq * 4 + rr], s);
    }
}

// ---------------- out-GEMM (gload_lds): out = rs[row]*(y @ (Wo*g)^T) ------
__global__ __launch_bounds__(256) void ogemm_h(
    const f16* __restrict__ y, const float* __restrict__ rowssq,
    const f16* __restrict__ Wogh, float* __restrict__ out, int m_base) {
  __shared__ f16 As[128][64];
  __shared__ f16 Bs[128][64];
  __shared__ float rsl[128];
  const int t = threadIdx.x;
  const int m0 = blockIdx.y * 128;
  const int n0 = blockIdx.x * 128;
  const int wave = t >> 6, lane = t & 63;
  const int wm = (wave >> 1) * 64, wn = (wave & 1) * 64;
  const int fr = lane & 15, fq = lane >> 4;
  const int fr7 = fr & 7;
  const int srow = lane >> 3;
  const int sc = (lane & 7) ^ srow;
  const char* Ab = (const char*)&As[0][0];
  const char* Bb = (const char*)&Bs[0][0];
  if (t < 128) rsl[t] = rsqrtf(rowssq[m0 + t] * (1.f / 256.f) + 1e-6f);
  f32x4 acc[4][4] = {};
#pragma unroll 1
  for (int kt = 0; kt < 4; ++kt) {
    const int k0 = kt * 64;
#pragma unroll
    for (int j = 0; j < 4; ++j) {
      int c = j * 4 + wave;
      int row = c * 8 + srow;
      gload16(y + (size_t)(m0 + row) * 256 + k0 + sc * 8, &As[0][0] + c * 512);
      gload16(Wogh + (size_t)(n0 + row) * 256 + k0 + sc * 8, &Bs[0][0] + c * 512);
    }
    __syncthreads();
#pragma unroll
    for (int ks = 0; ks < 2; ++ks) {
      const int p = ((ks * 4 + fq) ^ fr7) << 4;
      f16x8 afr[4], bfr[4];
#pragma unroll
      for (int mi = 0; mi < 4; ++mi)
        afr[mi] = *(const f16x8*)(Ab + (wm + mi * 16 + fr) * 128 + p);
#pragma unroll
      for (int ni = 0; ni < 4; ++ni)
        bfr[ni] = *(const f16x8*)(Bb + (wn + ni * 16 + fr) * 128 + p);
#pragma unroll
      for (int mi = 0; mi < 4; ++mi)
#pragma unroll
        for (int ni = 0; ni < 4; ++ni)
          acc[mi][ni] = __builtin_amdgcn_mfma_f32_16x16x32_f16(
              afr[mi], bfr[ni], acc[mi][ni], 0, 0, 0);
    }
    __syncthreads();
  }
#pragma unroll
  for (int mi = 0; mi < 4; ++mi)
#pragma unroll
    for (int rr = 0; rr < 4; ++rr) {
      int lrow = wm + mi * 16 + fq * 4 + rr;
      float rs = rsl[lrow];
#pragma unroll
      for (int ni = 0; ni < 4; ++ni) {
        int row = m_base + m0 + lrow;
        int col = n0 + wn + ni * 16 + fr;
        out[(size_t)row * 256 + col] = rs * acc[mi][ni][rr];
      }
    }
}

// ================= R9 fallback path (fp32 staging) =================
__global__ __launch_bounds__(256) void beta_xbsum(
    const float* __restrict__ x, const float* __restrict__ Wb,
    float* __restrict__ betaArr, float* __restrict__ xbsum) {
  const int t = threadIdx.x;
  const int wave = t >> 6, lane = t & 63;
  const int b = blockIdx.x >> 6;
  const int tile = blockIdx.x & 63;
  float4 wb[4];
#pragma unroll
  for (int h = 0; h < 4; ++h) wb[h] = *(const float4*)(Wb + h * 256 + lane * 4);
  float xacc[4][4] = {};
  const size_t rowbase = (size_t)b * 4096 + tile * 64;
  __shared__ float bsh[4][64];
  float4 xv = *(const float4*)(x + (rowbase + wave) * 256 + lane * 4);
#pragma unroll 2
  for (int i = 0; i < 16; ++i) {
    int r = i * 4 + wave;
    float4 nx = xv;
    if (i < 15)
      nx = *(const float4*)(x + (rowbase + r + 4) * 256 + lane * 4);
#pragma unroll
    for (int h = 0; h < 4; ++h) {
      float s = xv.x * wb[h].x + xv.y * wb[h].y + xv.z * wb[h].z + xv.w * wb[h].w;
#pragma unroll
      for (int off = 32; off; off >>= 1) s += __shfl_xor(s, off);
      float bh = 1.f / (1.f + __expf(-s));
      if (lane == h) bsh[h][r] = bh;
      xacc[h][0] += bh * xv.x; xacc[h][1] += bh * xv.y;
      xacc[h][2] += bh * xv.z; xacc[h][3] += bh * xv.w;
    }
    xv = nx;
  }
  __shared__ float xbp[4][4][256];
#pragma unroll
  for (int h = 0; h < 4; ++h)
#pragma unroll
    for (int j = 0; j < 4; ++j) xbp[wave][h][lane * 4 + j] = xacc[h][j];
  __syncthreads();
  {
    int h = t >> 6, r = t & 63;
    betaArr[((size_t)(b * 4 + h) << 12) + tile * 64 + r] = bsh[h][r];
  }
  for (int idx = t; idx < 1024; idx += 256) {
    int h = idx >> 8, c = idx & 255;
    float s = xbp[0][h][c] + xbp[1][h][c] + xbp[2][h][c] + xbp[3][h][c];
    atomicAdd(&xbsum[(b * 4 + h) * 256 + c], s);
  }
}

__global__ __launch_bounds__(256) void kgemm_sums(
    const float* __restrict__ x, const float* __restrict__ Wk,
    const float* __restrict__ betaArr,
    float* __restrict__ ksum, float* __restrict__ kbsum) {
  __shared__ union {
    struct { f16 A[128][72]; f16 B[128][72]; } s;
    f16 K[128][132];
  } u;
  __shared__ float bstage[2][128];
  const int t = threadIdx.x;
  const int m0 = blockIdx.y * 128;
  const int n0 = blockIdx.x * 128;
  const int b = m0 >> 12;
  const int wave = t >> 6, lane = t & 63;
  const int wm = (wave >> 1) * 64, wn = (wave & 1) * 64;
  const int fr = lane & 15, fq = lane >> 4;
  {
    int hh = t >> 7, r = t & 127;
    bstage[hh][r] =
        betaArr[((size_t)(b * 4 + (n0 >> 6) + hh) << 12) + (m0 & 4095) + r];
  }
  f32x4 acc[4][4] = {};
#pragma unroll 1
  for (int kt = 0; kt < 4; ++kt) {
    const int k0 = kt * 64;
#pragma unroll
    for (int i = 0; i < 4; ++i) {
      int id = i * 256 + t;
      int row = id >> 3, cc = id & 7;
      *(f16x8*)&u.s.A[row][cc * 8] =
          cvt8(x + (size_t)(m0 + row) * 256 + k0 + cc * 8);
      *(f16x8*)&u.s.B[row][cc * 8] =
          cvt8(Wk + (size_t)(n0 + row) * 256 + k0 + cc * 8);
    }
    __syncthreads();
#pragma unroll
    for (int ks = 0; ks < 2; ++ks) {
      f16x8 afr[4], bfr[4];
#pragma unroll
      for (int mi = 0; mi < 4; ++mi)
        afr[mi] = *(const f16x8*)&u.s.A[wm + mi * 16 + fr][ks * 32 + fq * 8];
#pragma unroll
      for (int ni = 0; ni < 4; ++ni)
        bfr[ni] = *(const f16x8*)&u.s.B[wn + ni * 16 + fr][ks * 32 + fq * 8];
#pragma unroll
      for (int mi = 0; mi < 4; ++mi)
#pragma unroll
        for (int ni = 0; ni < 4; ++ni)
          acc[mi][ni] = __builtin_amdgcn_mfma_f32_16x16x32_f16(
              afr[mi], bfr[ni], acc[mi][ni], 0, 0, 0);
    }
    __syncthreads();
  }
#pragma unroll
  for (int mi = 0; mi < 4; ++mi)
#pragma unroll
    for (int rr = 0; rr < 4; ++rr) {
      float s = 0.f;
#pragma unroll
      for (int ni = 0; ni < 4; ++ni) {
        float v = acc[mi][ni][rr];
        v = v > 0.f ? v + 1.f : __expf(v);
        acc[mi][ni][rr] = v;
        s += v * v;
      }
#pragma unroll
      for (int off = 1; off < 16; off <<= 1) s += __shfl_xor(s, off);
      float inv = 1.f / (sqrtf(s) + 1e-6f);
#pragma unroll
      for (int ni = 0; ni < 4; ++ni) acc[mi][ni][rr] *= inv;
    }
#pragma unroll
  for (int mi = 0; mi < 4; ++mi)
#pragma unroll
    for (int ni = 0; ni < 4; ++ni)
#pragma unroll
      for (int rr = 0; rr < 4; ++rr)
        u.K[wm + mi * 16 + fq * 4 + rr][wn + ni * 16 + fr] = (f16)acc[mi][ni][rr];
  __syncthreads();
  if (t < 128) {
    const int c = t, hl = c >> 6;
    float sk = 0.f, skb = 0.f;
#pragma unroll 4
    for (int r = 0; r < 128; ++r) {
      float v = (float)u.K[r][c];
      float be = bstage[hl][r];
      sk += v;
      skb += be * v;
    }
    int gh = b * 4 + (n0 >> 6) + hl;
    atomicAdd(&ksum[gh * 64 + (c & 63)], sk);
    atomicAdd(&kbsum[gh * 64 + (c & 63)], skb);
  }
}

__global__ __launch_bounds__(256) void ygemm_ssq(
    const float* __restrict__ x, int m_base, const f16* __restrict__ M,
    f16* __restrict__ y, float* __restrict__ rowssq) {
  __shared__ f16 As[128][72];
  __shared__ f16 Bs[128][72];
  const int t = threadIdx.x;
  const int m0 = blockIdx.y * 128;
  const int n0 = blockIdx.x * 128;
  const int b = (m_base + m0) >> 12;
  const f16* Mb = M + (size_t)b * 65536;
  const int wave = t >> 6, lane = t & 63;
  const int wm = (wave >> 1) * 64, wn = (wave & 1) * 64;
  const int fr = lane & 15, fq = lane >> 4;
  f32x4 acc[4][4] = {};
#pragma unroll 1
  for (int kt = 0; kt < 4; ++kt) {
    const int k0 = kt * 64;
#pragma unroll
    for (int i = 0; i < 4; ++i) {
      int id = i * 256 + t;
      int row = id >> 3, cc = id & 7;
      *(f16x8*)&As[row][cc * 8] =
          cvt8(x + (size_t)(m_base + m0 + row) * 256 + k0 + cc * 8);
      *(uint4*)&Bs[row][cc * 8] =
          *(const uint4*)(Mb + (size_t)(n0 + row) * 256 + k0 + cc * 8);
    }
    __syncthreads();
#pragma unroll
    for (int ks = 0; ks < 2; ++ks) {
      f16x8 afr[4], bfr[4];
#pragma unroll
      for (int mi = 0; mi < 4; ++mi)
        afr[mi] = *(const f16x8*)&As[wm + mi * 16 + fr][ks * 32 + fq * 8];
#pragma unroll
      for (int ni = 0; ni < 4; ++ni)
        bfr[ni] = *(const f16x8*)&Bs[wn + ni * 16 + fr][ks * 32 + fq * 8];
#pragma unroll
      for (int mi = 0; mi < 4; ++mi)
#pragma unroll
        for (int ni = 0; ni < 4; ++ni)
          acc[mi][ni] = __builtin_amdgcn_mfma_f32_16x16x32_f16(
              afr[mi], bfr[ni], acc[mi][ni], 0, 0, 0);
    }
    __syncthreads();
  }
#pragma unroll
  for (int mi = 0; mi < 4; ++mi)
#pragma unroll
    for (int rr = 0; rr < 4; ++rr) {
      float s = 0.f;
#pragma unroll
      for (int ni = 0; ni < 4; ++ni) {
        float v = acc[mi][ni][rr];
        s += v * v;
        int row = m0 + wm + mi * 16 + fq * 4 + rr;
        int col = n0 + wn + ni * 16 + fr;
        y[(size_t)row * 256 + col] = (f16)v;
      }
#pragma unroll
      for (int off = 1; off < 16; off <<= 1) s += __shfl_xor(s, off);
      if (fr == 0)
        atomicAdd(&rowssq[m0 + wm + mi * 16 + fq * 4 + rr], s);
    }
}

__global__ __launch_bounds__(256) void ogemm_scaled(
    const f16* __restrict__ y, const float* __restrict__ rowssq,
    const float* __restrict__ g_rms, const float* __restrict__ Wo,
    float* __restrict__ out, int m_base) {
  __shared__ f16 As[128][72];
  __shared__ f16 Bs[128][72];
  const int t = threadIdx.x;
  const int m0 = blockIdx.y * 128;
  const int n0 = blockIdx.x * 128;
  const int wave = t >> 6, lane = t & 63;
  const int wm = (wave >> 1) * 64, wn = (wave & 1) * 64;
  const int fr = lane & 15, fq = lane >> 4;
  f32x4 acc[4][4] = {};
#pragma unroll 1
  for (int kt = 0; kt < 4; ++kt) {
    const int k0 = kt * 64;
#pragma unroll
    for (int i = 0; i < 4; ++i) {
      int id = i * 256 + t;
      int row = id >> 3, cc = id & 7;
      float rs = rsqrtf(rowssq[m0 + row] * (1.f / 256.f) + 1e-6f);
      const f16* yp = y + (size_t)(m0 + row) * 256 + k0 + cc * 8;
      const float* gp = g_rms + k0 + cc * 8;
      f16x8 a;
#pragma unroll
      for (int j = 0; j < 8; ++j) a[j] = (f16)((float)yp[j] * rs * gp[j]);
      *(f16x8*)&As[row][cc * 8] = a;
      *(f16x8*)&Bs[row][cc * 8] =
          cvt8(Wo + (size_t)(n0 + row) * 256 + k0 + cc * 8);
    }
    __syncthreads();
#pragma unroll
    for (int ks = 0; ks < 2; ++ks) {
      f16x8 afr[4], bfr[4];
#pragma unroll
      for (int mi = 0; mi < 4; ++mi)
        afr[mi] = *(const f16x8*)&As[wm + mi * 16 + fr][ks * 32 + fq * 8];
#pragma unroll
      for (int ni = 0; ni < 4; ++ni)
        bfr[ni] = *(const f16x8*)&Bs[wn + ni * 16 + fr][ks * 32 + fq * 8];
#pragma unroll
      for (int mi = 0; mi < 4; ++mi)
#pragma unroll
        for (int ni = 0; ni < 4; ++ni)
          acc[mi][ni] = __builtin_amdgcn_mfma_f32_16x16x32_f16(
              afr[mi], bfr[ni], acc[mi][ni], 0, 0, 0);
    }
    __syncthreads();
  }
#pragma unroll
  for (int mi = 0; mi < 4; ++mi)
#pragma unroll
    for (int ni = 0; ni < 4; ++ni)
#pragma unroll
      for (int rr = 0; rr < 4; ++rr) {
        int row = m_base + m0 + wm + mi * 16 + fq * 4 + rr;
        int col = n0 + wn + ni * 16 + fr;
        out[(size_t)row * 256 + col] = acc[mi][ni][rr];
      }
}

// ---------------- finalize S ----------------
__global__ __launch_bounds__(256) void finalize_S(
    const float* __restrict__ S, const float* __restrict__ Wv,
    const float* __restrict__ xbsum, const float* __restrict__ ksum,
    const float* __restrict__ kbsum, float* __restrict__ Sout) {
  const int bh = blockIdx.x;
  const int h = bh & 3;
  const int t = threadIdx.x;
  const int wave = t >> 6, lane = t & 63;
  __shared__ float xb[256], kb[64], key[64], errv[64];
  xb[t] = xbsum[bh * 256 + t];
  if (t < 64) {
    kb[t] = kbsum[bh * 64 + t];
    key[t] = ksum[bh * 64 + t] * (1.f / 4096.f);
  }
  __syncthreads();
#pragma unroll 1
  for (int ri = 0; ri < 16; ++ri) {
    int i = wave * 16 + ri;
    float4 wv4 = *(const float4*)(Wv + (size_t)(h * 64 + i) * 256 + lane * 4);
    float4 xb4 = *(const float4*)(&xb[lane * 4]);
    float s = wv4.x * xb4.x + wv4.y * xb4.y + wv4.z * xb4.z + wv4.w * xb4.w;
    s -= 0.95f * S[(size_t)bh * 4096 + i * 64 + lane] * kb[lane];
#pragma unroll
    for (int off = 32; off; off >>= 1) s += __shfl_xor(s, off);
    if (lane == 0) errv[i] = s * (1.f / 4096.f);
  }
  __syncthreads();
  for (int idx = t; idx < 4096; idx += 256) {
    int i = idx >> 6, j = idx & 63;
    float v = 0.95f * S[(size_t)bh * 4096 + idx] + errv[i] * key[j];
    Sout[(size_t)bh * 4096 + idx] = fminf(10.f, fmaxf(-10.f, v));
  }
}

extern "C" void kernel_launch(void* const* d_in, const int* in_sizes, int n_in,
                              void* d_out, int out_size, void* d_ws, size_t ws_size,
                              hipStream_t stream) {
  const float* x  = (const float*)d_in[0];
  const float* S  = (const float*)d_in[1];
  const float* Wq = (const float*)d_in[2];
  const float* Wk = (const float*)d_in[3];
  const float* Wv = (const float*)d_in[4];
  const float* Wb = (const float*)d_in[5];
  const float* Wo = (const float*)d_in[6];
  const float* g  = (const float*)d_in[7];

  char* w = (char*)d_ws;
  float* betaArr = (float*)w;                    // 1,048,576 B
  f16*   M       = (f16*)(w + 1048576);          // 2,097,152 B
  f16*   y       = (f16*)(w + 3145728);          // 16,777,216 B (32768x256)
  float* rowssq  = (float*)(w + 19922944);       // 262,144 B (2 halves)
  float* xbsum   = (float*)(w + 20185088);       // 65,536 B
  float* ksum    = (float*)(w + 20250624);       // 16,384 B
  float* kbsum   = (float*)(w + 20267008);       // 16,384 B
  // R10 extension
  f16*   xh      = (f16*)(w + 20283392);         // 33,554,432 B (65536x256)
  f16*   Wkh     = (f16*)(w + 53837824);         // 131,072 B
  f16*   Wogh    = (f16*)(w + 53968896);         // 131,072 B
  const size_t WS_NEED = 54099968ull;

  float* out  = (float*)d_out;                   // [16,4096,256] fp32
  float* Sout = out + (size_t)16 * 4096 * 256;   // [16,4,64,64]  fp32

  hipMemsetAsync(w + 19922944, 0, 360448, stream);  // rowssq..kbsum

  if (ws_size >= WS_NEED) {
    prep_w<<<64, 256, 0, stream>>>(Wk, Wo, g, Wkh, Wogh);
    beta_xbsum_h<<<1024, 256, 0, stream>>>(x, Wb, betaArr, xbsum, xh);
    kgemm_h<<<dim3(2, 512), 256, 0, stream>>>(xh, Wkh, betaArr, ksum, kbsum);
    fold_M<<<dim3(8, 64), 256, 0, stream>>>(S, Wq, M);
    for (int half = 0; half < 2; ++half) {
      int m_base = half * 32768;
      ygemm_h<<<dim3(2, 256), 256, 0, stream>>>(xh, m_base, M, y,
                                                rowssq + half * 32768);
      ogemm_h<<<dim3(2, 256), 256, 0, stream>>>(y, rowssq + half * 32768,
                                                Wogh, out, m_base);
    }
  } else {
    beta_xbsum<<<1024, 256, 0, stream>>>(x, Wb, betaArr, xbsum);
    kgemm_sums<<<dim3(2, 512), 256, 0, stream>>>(x, Wk, betaArr, ksum, kbsum);
    fold_M<<<dim3(8, 64), 256, 0, stream>>>(S, Wq, M);
    for (int half = 0; half < 2; ++half) {
      int m_base = half * 32768;
      ygemm_ssq<<<dim3(2, 256), 256, 0, stream>>>(x, m_base, M, y,
                                                  rowssq + half * 32768);
      ogemm_scaled<<<dim3(2, 256), 256, 0, stream>>>(y, rowssq + half * 32768,
                                                     g, Wo, out, m_base);
    }
  }
  finalize_S<<<64, 256, 0, stream>>>(S, Wv, xbsum, ksum, kbsum, Sout);
}

// Round 7
// 225.681 us; speedup vs baseline: 1.4651x; 1.0411x over previous
//
#include <hip/hip_runtime.h>
#include <math.h>

// DeltaNetTemporal: B=16, N=4096, C=256, H=4, D=64.  All I/O fp32.
// R6: state_pass eliminated by linearity (fold+GEMM; v-GEMM eliminated).
// R7/R8: beta_xbsum latency fix: 330.6 -> 286.7 us.
// R9: fold_M re-parallelized: 286.7 -> 250.7 us.
// R10/R11: f16 pre-conversion (xh/Wkh/Wogh): 250.7 -> 235.8.
// R12: gload_lds staging + both-sides swizzle: kgemm dropped below the
//   harness 41.7us poison-fill (no longer in top-5); total ~flat (fill tax).
// R13: ygemm+ogemm FUSED into yogemm: per block, 64 rows x 256 cols of
//   y in registers -> cross-wave rowssq in LDS -> normalized f16 y-tile in
//   XOR-swizzled LDS (chunk ^= row&7; linear 512B-stride rows would be a
//   16-way conflict on phase-2 A reads) -> out-GEMM. Eliminates y HBM
//   round-trip (32MB), rowssq atomics+memset, 2 dispatch ramps, halves.
// Pipeline: memset -> prep_w -> beta+xbsum(+xh) -> kGEMM -> fold M ->
//           yogemm -> finalize.

typedef _Float16 f16;
typedef f16 f16x8 __attribute__((ext_vector_type(8)));
typedef f16 f16x4 __attribute__((ext_vector_type(4)));
typedef float f32x4 __attribute__((ext_vector_type(4)));

typedef const __attribute__((address_space(1))) void gvoid;
typedef __attribute__((address_space(3))) void svoid;

// async global->LDS, 16B/lane; LDS dest is wave-uniform base + lane*16.
__device__ __forceinline__ void gload16(const void* g, void* l) {
  __builtin_amdgcn_global_load_lds((gvoid*)g, (svoid*)l, 16, 0, 0);
}

__device__ __forceinline__ f16x8 cvt8(const float* q) {
  float4 a = *(const float4*)q;
  float4 b = *(const float4*)(q + 4);
  f16x8 r;
  r[0] = (f16)a.x; r[1] = (f16)a.y; r[2] = (f16)a.z; r[3] = (f16)a.w;
  r[4] = (f16)b.x; r[5] = (f16)b.y; r[6] = (f16)b.z; r[7] = (f16)b.w;
  return r;
}

// ---------------- prep: Wkh = f16(Wk); Wogh = f16(Wo * g) ----------------
__global__ __launch_bounds__(256) void prep_w(
    const float* __restrict__ Wk, const float* __restrict__ Wo,
    const float* __restrict__ g, f16* __restrict__ Wkh,
    f16* __restrict__ Wogh) {
  int i = blockIdx.x * 256 + threadIdx.x;  // grid 64 -> 16384 threads
#pragma unroll
  for (int j = 0; j < 4; ++j) {
    int idx = i + j * 16384;  // 65536 elements each
    Wkh[idx] = (f16)Wk[idx];
    Wogh[idx] = (f16)(Wo[idx] * g[idx & 255]);
  }
}

// ---------------- beta + xbsum (+ xh store) ----------------
__global__ __launch_bounds__(256) void beta_xbsum_h(
    const float* __restrict__ x, const float* __restrict__ Wb,
    float* __restrict__ betaArr, float* __restrict__ xbsum,
    f16* __restrict__ xh) {
  const int t = threadIdx.x;
  const int wave = t >> 6, lane = t & 63;
  const int b = blockIdx.x >> 6;
  const int tile = blockIdx.x & 63;
  float4 wb[4];
#pragma unroll
  for (int h = 0; h < 4; ++h) wb[h] = *(const float4*)(Wb + h * 256 + lane * 4);
  float xacc[4][4] = {};
  const size_t rowbase = (size_t)b * 4096 + tile * 64;
  __shared__ float bsh[4][64];
  float4 xv = *(const float4*)(x + (rowbase + wave) * 256 + lane * 4);
#pragma unroll 2
  for (int i = 0; i < 16; ++i) {
    int r = i * 4 + wave;
    float4 nx = xv;
    if (i < 15)
      nx = *(const float4*)(x + (rowbase + r + 4) * 256 + lane * 4);
    f16x4 hx;
    hx[0] = (f16)xv.x; hx[1] = (f16)xv.y; hx[2] = (f16)xv.z; hx[3] = (f16)xv.w;
    *(f16x4*)(xh + (rowbase + r) * 256 + lane * 4) = hx;
#pragma unroll
    for (int h = 0; h < 4; ++h) {
      float s = xv.x * wb[h].x + xv.y * wb[h].y + xv.z * wb[h].z + xv.w * wb[h].w;
#pragma unroll
      for (int off = 32; off; off >>= 1) s += __shfl_xor(s, off);
      float bh = 1.f / (1.f + __expf(-s));
      if (lane == h) bsh[h][r] = bh;
      xacc[h][0] += bh * xv.x; xacc[h][1] += bh * xv.y;
      xacc[h][2] += bh * xv.z; xacc[h][3] += bh * xv.w;
    }
    xv = nx;
  }
  __shared__ float xbp[4][4][256];
#pragma unroll
  for (int h = 0; h < 4; ++h)
#pragma unroll
    for (int j = 0; j < 4; ++j) xbp[wave][h][lane * 4 + j] = xacc[h][j];
  __syncthreads();
  {
    int h = t >> 6, r = t & 63;
    betaArr[((size_t)(b * 4 + h) << 12) + tile * 64 + r] = bsh[h][r];
  }
  for (int idx = t; idx < 1024; idx += 256) {
    int h = idx >> 8, c = idx & 255;
    float s = xbp[0][h][c] + xbp[1][h][c] + xbp[2][h][c] + xbp[3][h][c];
    atomicAdd(&xbsum[(b * 4 + h) * 256 + c], s);
  }
}

// ---------------- k-GEMM (gload_lds staging) + elu/L2norm/col-sums --------
__global__ __launch_bounds__(256) void kgemm_h(
    const f16* __restrict__ xh, const f16* __restrict__ Wkh,
    const float* __restrict__ betaArr,
    float* __restrict__ ksum, float* __restrict__ kbsum) {
  __shared__ union {
    struct { f16 A[128][64]; f16 B[128][64]; } s;  // 32 KB staging
    f16 K[128][128];                               // 32 KB epilogue tile
  } u;
  __shared__ float bstage[2][128];
  const int t = threadIdx.x;
  const int m0 = blockIdx.y * 128;
  const int n0 = blockIdx.x * 128;
  const int b = m0 >> 12;
  const int wave = t >> 6, lane = t & 63;
  const int wm = (wave >> 1) * 64, wn = (wave & 1) * 64;
  const int fr = lane & 15, fq = lane >> 4;
  const int fr7 = fr & 7;
  const int srow = lane >> 3;
  const int sc = (lane & 7) ^ srow;
  {
    int hh = t >> 7, r = t & 127;
    bstage[hh][r] =
        betaArr[((size_t)(b * 4 + (n0 >> 6) + hh) << 12) + (m0 & 4095) + r];
  }
  const char* Ab = (const char*)&u.s.A[0][0];
  const char* Bb = (const char*)&u.s.B[0][0];
  f32x4 acc[4][4] = {};
#pragma unroll 1
  for (int kt = 0; kt < 4; ++kt) {
    const int k0 = kt * 64;
#pragma unroll
    for (int j = 0; j < 4; ++j) {
      int c = j * 4 + wave;
      int row = c * 8 + srow;
      gload16(xh + (size_t)(m0 + row) * 256 + k0 + sc * 8, &u.s.A[0][0] + c * 512);
      gload16(Wkh + (size_t)(n0 + row) * 256 + k0 + sc * 8, &u.s.B[0][0] + c * 512);
    }
    __syncthreads();
#pragma unroll
    for (int ks = 0; ks < 2; ++ks) {
      const int p = ((ks * 4 + fq) ^ fr7) << 4;
      f16x8 afr[4], bfr[4];
#pragma unroll
      for (int mi = 0; mi < 4; ++mi)
        afr[mi] = *(const f16x8*)(Ab + (wm + mi * 16 + fr) * 128 + p);
#pragma unroll
      for (int ni = 0; ni < 4; ++ni)
        bfr[ni] = *(const f16x8*)(Bb + (wn + ni * 16 + fr) * 128 + p);
#pragma unroll
      for (int mi = 0; mi < 4; ++mi)
#pragma unroll
        for (int ni = 0; ni < 4; ++ni)
          acc[mi][ni] = __builtin_amdgcn_mfma_f32_16x16x32_f16(
              afr[mi], bfr[ni], acc[mi][ni], 0, 0, 0);
    }
    __syncthreads();
  }
#pragma unroll
  for (int mi = 0; mi < 4; ++mi)
#pragma unroll
    for (int rr = 0; rr < 4; ++rr) {
      float s = 0.f;
#pragma unroll
      for (int ni = 0; ni < 4; ++ni) {
        float v = acc[mi][ni][rr];
        v = v > 0.f ? v + 1.f : __expf(v);
        acc[mi][ni][rr] = v;
        s += v * v;
      }
#pragma unroll
      for (int off = 1; off < 16; off <<= 1) s += __shfl_xor(s, off);
      float inv = 1.f / (sqrtf(s) + 1e-6f);
#pragma unroll
      for (int ni = 0; ni < 4; ++ni) acc[mi][ni][rr] *= inv;
    }
#pragma unroll
  for (int mi = 0; mi < 4; ++mi)
#pragma unroll
    for (int ni = 0; ni < 4; ++ni)
#pragma unroll
      for (int rr = 0; rr < 4; ++rr)
        u.K[wm + mi * 16 + fq * 4 + rr][wn + ni * 16 + fr] = (f16)acc[mi][ni][rr];
  __syncthreads();
  if (t < 128) {
    const int c = t, hl = c >> 6;
    float sk = 0.f, skb = 0.f;
#pragma unroll 4
    for (int r = 0; r < 128; ++r) {
      float v = (float)u.K[r][c];
      float be = bstage[hl][r];
      sk += v;
      skb += be * v;
    }
    int gh = b * 4 + (n0 >> 6) + hl;
    atomicAdd(&ksum[gh * 64 + (c & 63)], sk);
    atomicAdd(&kbsum[gh * 64 + (c & 63)], skb);
  }
}

// ---------------- fold: M[b][(h,d)][c] = 0.95 * S[b,h] @ Wq_h --------------
__global__ __launch_bounds__(256) void fold_M(
    const float* __restrict__ S, const float* __restrict__ Wq,
    f16* __restrict__ M) {
  const int bh = blockIdx.y;
  const int dq = blockIdx.x;
  const int h = bh & 3;
  const int t = threadIdx.x;
  const float* Sp = S + (size_t)bh * 4096 + dq * 8 * 64;
  const float* Wp = Wq + (size_t)h * 64 * 256 + t;
  float m[8] = {};
#pragma unroll 4
  for (int e = 0; e < 64; ++e) {
    float wv = Wp[e * 256];
#pragma unroll
    for (int dd = 0; dd < 8; ++dd) m[dd] += Sp[dd * 64 + e] * wv;
  }
  f16* Mb = M + (size_t)(bh >> 2) * 65536;
#pragma unroll
  for (int dd = 0; dd < 8; ++dd)
    Mb[(size_t)(h * 64 + dq * 8 + dd) * 256 + t] = (f16)(0.95f * m[dd]);
}

// ---------------- fused y+out GEMM ----------------
// Block: 64 rows x 256 cols. Phase 1: y = xh @ M[b]^T (reg), cross-wave
// rowssq -> rs; normalized f16 y-tile to swizzled LDS. Phase 2:
// out = yhat @ (Wo*g)^T. Wave w owns cols w*64..+63 in both phases.
__global__ __launch_bounds__(256) void yogemm_h(
    const f16* __restrict__ xh, const f16* __restrict__ M,
    const f16* __restrict__ Wogh, float* __restrict__ out) {
  __shared__ f16 Bst[256 * 64];   // 32 KB: M-tile (ph1) / Wog-tile (ph2)
  __shared__ f16 Ast[64 * 64];    // 8 KB: xh-tile (ph1)
  __shared__ f16 yl[64 * 256];    // 32 KB: normalized y, chunk^=(row&7)
  __shared__ float ssq[4][64];
  __shared__ float rs_l[64];
  const int t = threadIdx.x;
  const int m0 = blockIdx.x * 64;
  const int b = m0 >> 12;
  const f16* Mb = M + (size_t)b * 65536;
  const int wave = t >> 6, lane = t & 63;
  const int wn = wave * 64;
  const int fr = lane & 15, fq = lane >> 4;
  const int fr7 = fr & 7;
  const int srow = lane >> 3;
  const int sc = (lane & 7) ^ srow;
  const char* Ab = (const char*)Ast;
  const char* Bb = (const char*)Bst;
  f32x4 acc[4][4] = {};
  // ---- phase 1: y = xh[m0:m0+64,:] @ M^T ----
#pragma unroll 1
  for (int kt = 0; kt < 4; ++kt) {
    const int k0 = kt * 64;
    if (wave < 2) {  // A tile: 64x64 = 8 chunk-groups
      int c = wave * 4 + (lane >> 4);  // reuse lanes: 2 waves x 4 = 8 groups
      int l16 = lane & 15;             // 16 lanes x 4 rows... NO - keep simple
    }
    // A tile: 8 groups, j=0..1 over waves 0..3
#pragma unroll
    for (int j = 0; j < 2; ++j) {
      int c = j * 4 + wave;
      int row = c * 8 + srow;
      gload16(xh + (size_t)(m0 + row) * 256 + k0 + sc * 8, Ast + c * 512);
    }
    // B tile (M): 32 groups
#pragma unroll
    for (int j = 0; j < 8; ++j) {
      int c = j * 4 + wave;
      int row = c * 8 + srow;
      gload16(Mb + (size_t)row * 256 + k0 + sc * 8, Bst + c * 512);
    }
    __syncthreads();
#pragma unroll
    for (int ks = 0; ks < 2; ++ks) {
      const int p = ((ks * 4 + fq) ^ fr7) << 4;
      f16x8 afr[4], bfr[4];
#pragma unroll
      for (int mi = 0; mi < 4; ++mi)
        afr[mi] = *(const f16x8*)(Ab + (mi * 16 + fr) * 128 + p);
#pragma unroll
      for (int ni = 0; ni < 4; ++ni)
        bfr[ni] = *(const f16x8*)(Bb + (wn + ni * 16 + fr) * 128 + p);
#pragma unroll
      for (int mi = 0; mi < 4; ++mi)
#pragma unroll
        for (int ni = 0; ni < 4; ++ni)
          acc[mi][ni] = __builtin_amdgcn_mfma_f32_16x16x32_f16(
              afr[mi], bfr[ni], acc[mi][ni], 0, 0, 0);
    }
    __syncthreads();
  }
  // ---- rowssq across 4 waves ----
#pragma unroll
  for (int mi = 0; mi < 4; ++mi)
#pragma unroll
    for (int rr = 0; rr < 4; ++rr) {
      float s = 0.f;
#pragma unroll
      for (int ni = 0; ni < 4; ++ni) {
        float v = acc[mi][ni][rr];
        s += v * v;
      }
#pragma unroll
      for (int off = 1; off < 16; off <<= 1) s += __shfl_xor(s, off);
      if (fr == 0) ssq[wave][mi * 16 + fq * 4 + rr] = s;
    }
  __syncthreads();
  if (t < 64)
    rs_l[t] = rsqrtf((ssq[0][t] + ssq[1][t] + ssq[2][t] + ssq[3][t]) *
                         (1.f / 256.f) +
                     1e-6f);
  __syncthreads();
  // ---- normalize + write swizzled f16 y-tile ----
#pragma unroll
  for (int mi = 0; mi < 4; ++mi)
#pragma unroll
    for (int rr = 0; rr < 4; ++rr) {
      int row = mi * 16 + fq * 4 + rr;
      float rs = rs_l[row];
      int r7 = row & 7;
#pragma unroll
      for (int ni = 0; ni < 4; ++ni) {
        int col = wn + ni * 16 + fr;
        int idx = row * 256 + ((((col >> 3) ^ r7) << 3) | (col & 7));
        yl[idx] = (f16)(rs * acc[mi][ni][rr]);
      }
    }
  __syncthreads();
  // ---- phase 2: out = yhat @ Wog^T ----
#pragma unroll
  for (int mi = 0; mi < 4; ++mi)
#pragma unroll
    for (int ni = 0; ni < 4; ++ni) acc[mi][ni] = (f32x4){0.f, 0.f, 0.f, 0.f};
#pragma unroll 1
  for (int kt = 0; kt < 4; ++kt) {
    const int k0 = kt * 64;
#pragma unroll
    for (int j = 0; j < 8; ++j) {
      int c = j * 4 + wave;
      int row = c * 8 + srow;
      gload16(Wogh + (size_t)row * 256 + k0 + sc * 8, Bst + c * 512);
    }
    __syncthreads();
#pragma unroll
    for (int ks = 0; ks < 2; ++ks) {
      const int p = ((ks * 4 + fq) ^ fr7) << 4;
      f16x8 afr[4], bfr[4];
#pragma unroll
      for (int mi = 0; mi < 4; ++mi) {
        int row = mi * 16 + fr;
        int chunk = ((kt * 8 + ks * 4 + fq) ^ (row & 7)) << 4;
        afr[mi] = *(const f16x8*)((const char*)yl + row * 512 + chunk);
      }
#pragma unroll
      for (int ni = 0; ni < 4; ++ni)
        bfr[ni] = *(const f16x8*)(Bb + (wn + ni * 16 + fr) * 128 + p);
#pragma unroll
      for (int mi = 0; mi < 4; ++mi)
#pragma unroll
        for (int ni = 0; ni < 4; ++ni)
          acc[mi][ni] = __builtin_amdgcn_mfma_f32_16x16x32_f16(
              afr[mi], bfr[ni], acc[mi][ni], 0, 0, 0);
    }
    __syncthreads();
  }
#pragma unroll
  for (int mi = 0; mi < 4; ++mi)
#pragma unroll
    for (int ni = 0; ni < 4; ++ni)
#pragma unroll
      for (int rr = 0; rr < 4; ++rr) {
        int row = m0 + mi * 16 + fq * 4 + rr;
        int col = wn + ni * 16 + fr;
        out[(size_t)row * 256 + col] = acc[mi][ni][rr];
      }
}

// ================= R9 fallback path (fp32 staging) =================
__global__ __launch_bounds__(256) void beta_xbsum(
    const float* __restrict__ x, const float* __restrict__ Wb,
    float* __restrict__ betaArr, float* __restrict__ xbsum) {
  const int t = threadIdx.x;
  const int wave = t >> 6, lane = t & 63;
  const int b = blockIdx.x >> 6;
  const int tile = blockIdx.x & 63;
  float4 wb[4];
#pragma unroll
  for (int h = 0; h < 4; ++h) wb[h] = *(const float4*)(Wb + h * 256 + lane * 4);
  float xacc[4][4] = {};
  const size_t rowbase = (size_t)b * 4096 + tile * 64;
  __shared__ float bsh[4][64];
  float4 xv = *(const float4*)(x + (rowbase + wave) * 256 + lane * 4);
#pragma unroll 2
  for (int i = 0; i < 16; ++i) {
    int r = i * 4 + wave;
    float4 nx = xv;
    if (i < 15)
      nx = *(const float4*)(x + (rowbase + r + 4) * 256 + lane * 4);
#pragma unroll
    for (int h = 0; h < 4; ++h) {
      float s = xv.x * wb[h].x + xv.y * wb[h].y + xv.z * wb[h].z + xv.w * wb[h].w;
#pragma unroll
      for (int off = 32; off; off >>= 1) s += __shfl_xor(s, off);
      float bh = 1.f / (1.f + __expf(-s));
      if (lane == h) bsh[h][r] = bh;
      xacc[h][0] += bh * xv.x; xacc[h][1] += bh * xv.y;
      xacc[h][2] += bh * xv.z; xacc[h][3] += bh * xv.w;
    }
    xv = nx;
  }
  __shared__ float xbp[4][4][256];
#pragma unroll
  for (int h = 0; h < 4; ++h)
#pragma unroll
    for (int j = 0; j < 4; ++j) xbp[wave][h][lane * 4 + j] = xacc[h][j];
  __syncthreads();
  {
    int h = t >> 6, r = t & 63;
    betaArr[((size_t)(b * 4 + h) << 12) + tile * 64 + r] = bsh[h][r];
  }
  for (int idx = t; idx < 1024; idx += 256) {
    int h = idx >> 8, c = idx & 255;
    float s = xbp[0][h][c] + xbp[1][h][c] + xbp[2][h][c] + xbp[3][h][c];
    atomicAdd(&xbsum[(b * 4 + h) * 256 + c], s);
  }
}

__global__ __launch_bounds__(256) void kgemm_sums(
    const float* __restrict__ x, const float* __restrict__ Wk,
    const float* __restrict__ betaArr,
    float* __restrict__ ksum, float* __restrict__ kbsum) {
  __shared__ union {
    struct { f16 A[128][72]; f16 B[128][72]; } s;
    f16 K[128][132];
  } u;
  __shared__ float bstage[2][128];
  const int t = threadIdx.x;
  const int m0 = blockIdx.y * 128;
  const int n0 = blockIdx.x * 128;
  const int b = m0 >> 12;
  const int wave = t >> 6, lane = t & 63;
  const int wm = (wave >> 1) * 64, wn = (wave & 1) * 64;
  const int fr = lane & 15, fq = lane >> 4;
  {
    int hh = t >> 7, r = t & 127;
    bstage[hh][r] =
        betaArr[((size_t)(b * 4 + (n0 >> 6) + hh) << 12) + (m0 & 4095) + r];
  }
  f32x4 acc[4][4] = {};
#pragma unroll 1
  for (int kt = 0; kt < 4; ++kt) {
    const int k0 = kt * 64;
#pragma unroll
    for (int i = 0; i < 4; ++i) {
      int id = i * 256 + t;
      int row = id >> 3, cc = id & 7;
      *(f16x8*)&u.s.A[row][cc * 8] =
          cvt8(x + (size_t)(m0 + row) * 256 + k0 + cc * 8);
      *(f16x8*)&u.s.B[row][cc * 8] =
          cvt8(Wk + (size_t)(n0 + row) * 256 + k0 + cc * 8);
    }
    __syncthreads();
#pragma unroll
    for (int ks = 0; ks < 2; ++ks) {
      f16x8 afr[4], bfr[4];
#pragma unroll
      for (int mi = 0; mi < 4; ++mi)
        afr[mi] = *(const f16x8*)&u.s.A[wm + mi * 16 + fr][ks * 32 + fq * 8];
#pragma unroll
      for (int ni = 0; ni < 4; ++ni)
        bfr[ni] = *(const f16x8*)&u.s.B[wn + ni * 16 + fr][ks * 32 + fq * 8];
#pragma unroll
      for (int mi = 0; mi < 4; ++mi)
#pragma unroll
        for (int ni = 0; ni < 4; ++ni)
          acc[mi][ni] = __builtin_amdgcn_mfma_f32_16x16x32_f16(
              afr[mi], bfr[ni], acc[mi][ni], 0, 0, 0);
    }
    __syncthreads();
  }
#pragma unroll
  for (int mi = 0; mi < 4; ++mi)
#pragma unroll
    for (int rr = 0; rr < 4; ++rr) {
      float s = 0.f;
#pragma unroll
      for (int ni = 0; ni < 4; ++ni) {
        float v = acc[mi][ni][rr];
        v = v > 0.f ? v + 1.f : __expf(v);
        acc[mi][ni][rr] = v;
        s += v * v;
      }
#pragma unroll
      for (int off = 1; off < 16; off <<= 1) s += __shfl_xor(s, off);
      float inv = 1.f / (sqrtf(s) + 1e-6f);
#pragma unroll
      for (int ni = 0; ni < 4; ++ni) acc[mi][ni][rr] *= inv;
    }
#pragma unroll
  for (int mi = 0; mi < 4; ++mi)
#pragma unroll
    for (int ni = 0; ni < 4; ++ni)
#pragma unroll
      for (int rr = 0; rr < 4; ++rr)
        u.K[wm + mi * 16 + fq * 4 + rr][wn + ni * 16 + fr] = (f16)acc[mi][ni][rr];
  __syncthreads();
  if (t < 128) {
    const int c = t, hl = c >> 6;
    float sk = 0.f, skb = 0.f;
#pragma unroll 4
    for (int r = 0; r < 128; ++r) {
      float v = (float)u.K[r][c];
      float be = bstage[hl][r];
      sk += v;
      skb += be * v;
    }
    int gh = b * 4 + (n0 >> 6) + hl;
    atomicAdd(&ksum[gh * 64 + (c & 63)], sk);
    atomicAdd(&kbsum[gh * 64 + (c & 63)], skb);
  }
}

__global__ __launch_bounds__(256) void ygemm_ssq(
    const float* __restrict__ x, int m_base, const f16* __restrict__ M,
    f16* __restrict__ y, float* __restrict__ rowssq) {
  __shared__ f16 As[128][72];
  __shared__ f16 Bs[128][72];
  const int t = threadIdx.x;
  const int m0 = blockIdx.y * 128;
  const int n0 = blockIdx.x * 128;
  const int b = (m_base + m0) >> 12;
  const f16* Mb = M + (size_t)b * 65536;
  const int wave = t >> 6, lane = t & 63;
  const int wm = (wave >> 1) * 64, wn = (wave & 1) * 64;
  const int fr = lane & 15, fq = lane >> 4;
  f32x4 acc[4][4] = {};
#pragma unroll 1
  for (int kt = 0; kt < 4; ++kt) {
    const int k0 = kt * 64;
#pragma unroll
    for (int i = 0; i < 4; ++i) {
      int id = i * 256 + t;
      int row = id >> 3, cc = id & 7;
      *(f16x8*)&As[row][cc * 8] =
          cvt8(x + (size_t)(m_base + m0 + row) * 256 + k0 + cc * 8);
      *(uint4*)&Bs[row][cc * 8] =
          *(const uint4*)(Mb + (size_t)(n0 + row) * 256 + k0 + cc * 8);
    }
    __syncthreads();
#pragma unroll
    for (int ks = 0; ks < 2; ++ks) {
      f16x8 afr[4], bfr[4];
#pragma unroll
      for (int mi = 0; mi < 4; ++mi)
        afr[mi] = *(const f16x8*)&As[wm + mi * 16 + fr][ks * 32 + fq * 8];
#pragma unroll
      for (int ni = 0; ni < 4; ++ni)
        bfr[ni] = *(const f16x8*)&Bs[wn + ni * 16 + fr][ks * 32 + fq * 8];
#pragma unroll
      for (int mi = 0; mi < 4; ++mi)
#pragma unroll
        for (int ni = 0; ni < 4; ++ni)
          acc[mi][ni] = __builtin_amdgcn_mfma_f32_16x16x32_f16(
              afr[mi], bfr[ni], acc[mi][ni], 0, 0, 0);
    }
    __syncthreads();
  }
#pragma unroll
  for (int mi = 0; mi < 4; ++mi)
#pragma unroll
    for (int rr = 0; rr < 4; ++rr) {
      float s = 0.f;
#pragma unroll
      for (int ni = 0; ni < 4; ++ni) {
        float v = acc[mi][ni][rr];
        s += v * v;
        int row = m0 + wm + mi * 16 + fq * 4 + rr;
        int col = n0 + wn + ni * 16 + fr;
        y[(size_t)row * 256 + col] = (f16)v;
      }
#pragma unroll
      for (int off = 1; off < 16; off <<= 1) s += __shfl_xor(s, off);
      if (fr == 0)
        atomicAdd(&rowssq[m0 + wm + mi * 16 + fq * 4 + rr], s);
    }
}

__global__ __launch_bounds__(256) void ogemm_scaled(
    const f16* __restrict__ y, const float* __restrict__ rowssq,
    const float* __restrict__ g_rms, const float* __restrict__ Wo,
    float* __restrict__ out, int m_base) {
  __shared__ f16 As[128][72];
  __shared__ f16 Bs[128][72];
  const int t = threadIdx.x;
  const int m0 = blockIdx.y * 128;
  const int n0 = blockIdx.x * 128;
  const int wave = t >> 6, lane = t & 63;
  const int wm = (wave >> 1) * 64, wn = (wave & 1) * 64;
  const int fr = lane & 15, fq = lane >> 4;
  f32x4 acc[4][4] = {};
#pragma unroll 1
  for (int kt = 0; kt < 4; ++kt) {
    const int k0 = kt * 64;
#pragma unroll
    for (int i = 0; i < 4; ++i) {
      int id = i * 256 + t;
      int row = id >> 3, cc = id & 7;
      float rs = rsqrtf(rowssq[m0 + row] * (1.f / 256.f) + 1e-6f);
      const f16* yp = y + (size_t)(m0 + row) * 256 + k0 + cc * 8;
      const float* gp = g_rms + k0 + cc * 8;
      f16x8 a;
#pragma unroll
      for (int j = 0; j < 8; ++j) a[j] = (f16)((float)yp[j] * rs * gp[j]);
      *(f16x8*)&As[row][cc * 8] = a;
      *(f16x8*)&Bs[row][cc * 8] =
          cvt8(Wo + (size_t)(n0 + row) * 256 + k0 + cc * 8);
    }
    __syncthreads();
#pragma unroll
    for (int ks = 0; ks < 2; ++ks) {
      f16x8 afr[4], bfr[4];
#pragma unroll
      for (int mi = 0; mi < 4; ++mi)
        afr[mi] = *(const f16x8*)&As[wm + mi * 16 + fr][ks * 32 + fq * 8];
#pragma unroll
      for (int ni = 0; ni < 4; ++ni)
        bfr[ni] = *(const f16x8*)&Bs[wn + ni * 16 + fr][ks * 32 + fq * 8];
#pragma unroll
      for (int mi = 0; mi < 4; ++mi)
#pragma unroll
        for (int ni = 0; ni < 4; ++ni)
          acc[mi][ni] = __builtin_amdgcn_mfma_f32_16x16x32_f16(
              afr[mi], bfr[ni], acc[mi][ni], 0, 0, 0);
    }
    __syncthreads();
  }
#pragma unroll
  for (int mi = 0; mi < 4; ++mi)
#pragma unroll
    for (int ni = 0; ni < 4; ++ni)
#pragma unroll
      for (int rr = 0; rr < 4; ++rr) {
        int row = m_base + m0 + wm + mi * 16 + fq * 4 + rr;
        int col = n0 + wn + ni * 16 + fr;
        out[(size_t)row * 256 + col] = acc[mi][ni][rr];
      }
}

// ---------------- finalize S ----------------
__global__ __launch_bounds__(256) void finalize_S(
    const float* __restrict__ S, const float* __restrict__ Wv,
    const float* __restrict__ xbsum, const float* __restrict__ ksum,
    const float* __restrict__ kbsum, float* __restrict__ Sout) {
  const int bh = blockIdx.x;
  const int h = bh & 3;
  const int t = threadIdx.x;
  const int wave = t >> 6, lane = t & 63;
  __shared__ float xb[256], kb[64], key[64], errv[64];
  xb[t] = xbsum[bh * 256 + t];
  if (t < 64) {
    kb[t] = kbsum[bh * 64 + t];
    key[t] = ksum[bh * 64 + t] * (1.f / 4096.f);
  }
  __syncthreads();
#pragma unroll 1
  for (int ri = 0; ri < 16; ++ri) {
    int i = wave * 16 + ri;
    float4 wv4 = *(const float4*)(Wv + (size_t)(h * 64 + i) * 256 + lane * 4);
    float4 xb4 = *(const float4*)(&xb[lane * 4]);
    float s = wv4.x * xb4.x + wv4.y * xb4.y + wv4.z * xb4.z + wv4.w * xb4.w;
    s -= 0.95f * S[(size_t)bh * 4096 + i * 64 + lane] * kb[lane];
#pragma unroll
    for (int off = 32; off; off >>= 1) s += __shfl_xor(s, off);
    if (lane == 0) errv[i] = s * (1.f / 4096.f);
  }
  __syncthreads();
  for (int idx = t; idx < 4096; idx += 256) {
    int i = idx >> 6, j = idx & 63;
    float v = 0.95f * S[(size_t)bh * 4096 + idx] + errv[i] * key[j];
    Sout[(size_t)bh * 4096 + idx] = fminf(10.f, fmaxf(-10.f, v));
  }
}

extern "C" void kernel_launch(void* const* d_in, const int* in_sizes, int n_in,
                              void* d_out, int out_size, void* d_ws, size_t ws_size,
                              hipStream_t stream) {
  const float* x  = (const float*)d_in[0];
  const float* S  = (const float*)d_in[1];
  const float* Wq = (const float*)d_in[2];
  const float* Wk = (const float*)d_in[3];
  const float* Wv = (const float*)d_in[4];
  const float* Wb = (const float*)d_in[5];
  const float* Wo = (const float*)d_in[6];
  const float* g  = (const float*)d_in[7];

  char* w = (char*)d_ws;
  float* betaArr = (float*)w;                    // 1,048,576 B
  f16*   M       = (f16*)(w + 1048576);          // 2,097,152 B
  f16*   y       = (f16*)(w + 3145728);          // 16,777,216 B (fallback only)
  float* rowssq  = (float*)(w + 19922944);       // 262,144 B (fallback only)
  float* xbsum   = (float*)(w + 20185088);       // 65,536 B
  float* ksum    = (float*)(w + 20250624);       // 16,384 B
  float* kbsum   = (float*)(w + 20267008);       // 16,384 B
  f16*   xh      = (f16*)(w + 20283392);         // 33,554,432 B (65536x256)
  f16*   Wkh     = (f16*)(w + 53837824);         // 131,072 B
  f16*   Wogh    = (f16*)(w + 53968896);         // 131,072 B
  const size_t WS_NEED = 54099968ull;

  float* out  = (float*)d_out;                   // [16,4096,256] fp32
  float* Sout = out + (size_t)16 * 4096 * 256;   // [16,4,64,64]  fp32

  if (ws_size >= WS_NEED) {
    hipMemsetAsync(w + 20185088, 0, 98304, stream);  // xbsum..kbsum
    prep_w<<<64, 256, 0, stream>>>(Wk, Wo, g, Wkh, Wogh);
    beta_xbsum_h<<<1024, 256, 0, stream>>>(x, Wb, betaArr, xbsum, xh);
    kgemm_h<<<dim3(2, 512), 256, 0, stream>>>(xh, Wkh, betaArr, ksum, kbsum);
    fold_M<<<dim3(8, 64), 256, 0, stream>>>(S, Wq, M);
    yogemm_h<<<1024, 256, 0, stream>>>(xh, M, Wogh, out);
  } else {
    hipMemsetAsync(w + 19922944, 0, 360448, stream);  // rowssq..kbsum
    beta_xbsum<<<1024, 256, 0, stream>>>(x, Wb, betaArr, xbsum);
    kgemm_sums<<<dim3(2, 512), 256, 0, stream>>>(x, Wk, betaArr, ksum, kbsum);
    fold_M<<<dim3(8, 64), 256, 0, stream>>>(S, Wq, M);
    for (int half = 0; half < 2; ++half) {
      int m_base = half * 32768;
      ygemm_ssq<<<dim3(2, 256), 256, 0, stream>>>(x, m_base, M, y,
                                                  rowssq + half * 32768);
      ogemm_scaled<<<dim3(2, 256), 256, 0, stream>>>(y, rowssq + half * 32768,
                                                     g, Wo, out, m_base);
    }
  }
  finalize_S<<<64, 256, 0, stream>>>(S, Wv, xbsum, ksum, kbsum, Sout);
}